// Round 1
// baseline (1114.697 us; speedup 1.0000x reference)
//
#include <hip/hip_runtime.h>
#include <hip/hip_bf16.h>

// Problem constants (match reference)
#define NNODES 50000
#define NEDGES 500000
#define INCH 128
#define HID 64
#define HEADS 4
#define FDIM 256          // HEADS*HID
#define NGRAPHS 64
#define OUTCH 16
#define NEG_SLOPE 0.2f

// ---------------- CSR build ----------------

__global__ void k_hist(const int* __restrict__ dst, int E, int* __restrict__ counts) {
    int i = blockIdx.x * blockDim.x + threadIdx.x;
    if (i < E) atomicAdd(&counts[dst[i]], 1);
}

__global__ __launch_bounds__(1024) void k_scan(const int* __restrict__ counts, int N,
                                               int* __restrict__ rowstart) {
    __shared__ int sums[1024];
    int t = threadIdx.x;
    const int CH = (N + 1023) / 1024;
    int base = t * CH;
    int s = 0;
    for (int i = 0; i < CH; ++i) {
        int idx = base + i;
        if (idx < N) s += counts[idx];
    }
    sums[t] = s;
    __syncthreads();
    for (int off = 1; off < 1024; off <<= 1) {
        int v = (t >= off) ? sums[t - off] : 0;
        __syncthreads();
        sums[t] += v;
        __syncthreads();
    }
    int prefix = (t == 0) ? 0 : sums[t - 1];
    if (t == 0) rowstart[0] = 0;
    for (int i = 0; i < CH; ++i) {
        int idx = base + i;
        if (idx < N) {
            prefix += counts[idx];
            rowstart[idx + 1] = prefix;
        }
    }
}

__global__ void k_scatter(const int* __restrict__ src, const int* __restrict__ dst, int E,
                          const int* __restrict__ rowstart, int* __restrict__ cursor,
                          int* __restrict__ csr_src) {
    int i = blockIdx.x * blockDim.x + threadIdx.x;
    if (i < E) {
        int d = dst[i];
        int p = atomicAdd(&cursor[d], 1);
        csr_src[rowstart[d] + p] = src[i];
    }
}

// ---------------- fp32 GEMM: C[M x 256] = A[M x K] * B[K x 256] ----------------

__global__ __launch_bounds__(256) void k_gemm(const float* __restrict__ A,
                                              const float* __restrict__ B,
                                              float* __restrict__ C, int M, int K) {
    __shared__ float As[32][65];  // [k][row], padded: conflict-free store & read
    __shared__ float Bs[32][64];  // [k][col]
    int tid = threadIdx.x;
    int tx = tid & 15, ty = tid >> 4;
    int row0 = blockIdx.x * 64, col0 = blockIdx.y * 64;
    float acc[4][4] = {};
    for (int k0 = 0; k0 < K; k0 += 32) {
#pragma unroll
        for (int l = 0; l < 8; ++l) {
            int idx = tid + l * 256;
            int r = idx >> 5, c = idx & 31;
            int gr = row0 + r;
            As[c][r] = (gr < M) ? A[(long)gr * K + k0 + c] : 0.f;
        }
#pragma unroll
        for (int l = 0; l < 8; ++l) {
            int idx = tid + l * 256;
            int r = idx >> 6, c = idx & 63;
            Bs[r][c] = B[(k0 + r) * FDIM + col0 + c];
        }
        __syncthreads();
#pragma unroll
        for (int kk = 0; kk < 32; ++kk) {
            float a0 = As[kk][ty * 4 + 0];
            float a1 = As[kk][ty * 4 + 1];
            float a2 = As[kk][ty * 4 + 2];
            float a3 = As[kk][ty * 4 + 3];
            float4 bv = *reinterpret_cast<const float4*>(&Bs[kk][tx * 4]);
            acc[0][0] += a0 * bv.x; acc[0][1] += a0 * bv.y; acc[0][2] += a0 * bv.z; acc[0][3] += a0 * bv.w;
            acc[1][0] += a1 * bv.x; acc[1][1] += a1 * bv.y; acc[1][2] += a1 * bv.z; acc[1][3] += a1 * bv.w;
            acc[2][0] += a2 * bv.x; acc[2][1] += a2 * bv.y; acc[2][2] += a2 * bv.z; acc[2][3] += a2 * bv.w;
            acc[3][0] += a3 * bv.x; acc[3][1] += a3 * bv.y; acc[3][2] += a3 * bv.z; acc[3][3] += a3 * bv.w;
        }
        __syncthreads();
    }
#pragma unroll
    for (int i = 0; i < 4; ++i) {
        int gr = row0 + ty * 4 + i;
        if (gr < M) {
            float4 v = make_float4(acc[i][0], acc[i][1], acc[i][2], acc[i][3]);
            *reinterpret_cast<float4*>(&C[(long)gr * FDIM + col0 + tx * 4]) = v;
        }
    }
}

// ---------------- per-node attention scores ----------------

__global__ __launch_bounds__(256) void k_scores(const float* __restrict__ h,
                                                const float* __restrict__ asrc,
                                                const float* __restrict__ adst,
                                                float* __restrict__ ssrc,
                                                float* __restrict__ sdst, int N) {
    int wave = threadIdx.x >> 6, lane = threadIdx.x & 63;
    int n = blockIdx.x * 4 + wave;
    if (n >= N) return;
#pragma unroll
    for (int hd = 0; hd < HEADS; ++hd) {
        float v = h[(long)n * FDIM + hd * HID + lane];
        float p = v * asrc[hd * HID + lane];
        float q = v * adst[hd * HID + lane];
#pragma unroll
        for (int off = 32; off; off >>= 1) {
            p += __shfl_xor(p, off);
            q += __shfl_xor(q, off);
        }
        if (lane == 0) {
            ssrc[n * HEADS + hd] = p;
            sdst[n * HEADS + hd] = q;
        }
    }
}

// ---------------- flash softmax + aggregation, one wave per (node, head) ----------------

__global__ __launch_bounds__(256) void k_aggregate(const float* __restrict__ h,
                                                   const float* __restrict__ ssrc,
                                                   const float* __restrict__ sdst,
                                                   const int* __restrict__ rowstart,
                                                   const int* __restrict__ csr_src,
                                                   const float* __restrict__ b,
                                                   float* __restrict__ out, int N) {
    int n = blockIdx.x;
    int hd = threadIdx.x >> 6, lane = threadIdx.x & 63;
    float sd = sdst[n * HEADS + hd];
    // self-loop initializes the online-softmax state
    float e = ssrc[n * HEADS + hd] + sd;
    e = (e > 0.f) ? e : NEG_SLOPE * e;
    float m = e, d = 1.0f;
    float acc = h[(long)n * FDIM + hd * HID + lane];
    int r0 = rowstart[n], r1 = rowstart[n + 1];
    for (int r = r0; r < r1; ++r) {
        int s = csr_src[r];
        float sc = ssrc[s * HEADS + hd] + sd;
        sc = (sc > 0.f) ? sc : NEG_SLOPE * sc;
        float hv = h[(long)s * FDIM + hd * HID + lane];
        if (sc > m) {
            float scale = expf(m - sc);
            acc = acc * scale + hv;
            d = d * scale + 1.0f;
            m = sc;
        } else {
            float w = expf(sc - m);
            d += w;
            acc += w * hv;
        }
    }
    out[(long)n * FDIM + hd * HID + lane] = fmaxf(acc / d + b[hd * HID + lane], 0.f);
}

// ---------------- pooling (batch sorted) ----------------

__global__ __launch_bounds__(256) void k_pool(const float* __restrict__ h,
                                              const int* __restrict__ batch,
                                              float* __restrict__ pooled, int N) {
    int f = threadIdx.x;
    int n0 = blockIdx.x * 128;
    if (n0 >= N) return;
    int n1 = min(n0 + 128, N);
    int g = batch[n0];
    float run = 0.f;
    for (int n = n0; n < n1; ++n) {
        int gn = batch[n];
        if (gn != g) {
            atomicAdd(&pooled[g * FDIM + f], run);
            run = 0.f;
            g = gn;
        }
        run += h[(long)n * FDIM + f];
    }
    atomicAdd(&pooled[g * FDIM + f], run);
}

// ---------------- final classifier: out[64x16] = pooled[64x256] @ Wc + bc ----------------

__global__ __launch_bounds__(256) void k_final(const float* __restrict__ pooled,
                                               const float* __restrict__ Wc,
                                               const float* __restrict__ bc,
                                               float* __restrict__ out) {
    int tid = blockIdx.x * 256 + threadIdx.x;  // 0..1023
    int g = tid >> 4, o = tid & 15;
    float s = bc[o];
    for (int k = 0; k < FDIM; ++k) s += pooled[g * FDIM + k] * Wc[k * OUTCH + o];
    out[g * OUTCH + o] = s;
}

// ---------------- launch ----------------

extern "C" void kernel_launch(void* const* d_in, const int* in_sizes, int n_in,
                              void* d_out, int out_size, void* d_ws, size_t ws_size,
                              hipStream_t stream) {
    const float* x = (const float*)d_in[0];
    const int* edge_index = (const int*)d_in[2];
    const int* batch = (const int*)d_in[3];
    const float* W[3]    = {(const float*)d_in[4], (const float*)d_in[8],  (const float*)d_in[12]};
    const float* asrc[3] = {(const float*)d_in[5], (const float*)d_in[9],  (const float*)d_in[13]};
    const float* adst[3] = {(const float*)d_in[6], (const float*)d_in[10], (const float*)d_in[14]};
    const float* bias[3] = {(const float*)d_in[7], (const float*)d_in[11], (const float*)d_in[15]};
    const float* Wc = (const float*)d_in[16];
    const float* bc = (const float*)d_in[17];

    const int N = in_sizes[3];          // 50000
    const int E = in_sizes[2] / 2;      // 500000
    const int* e_src = edge_index;
    const int* e_dst = edge_index + E;

    char* ws = (char*)d_ws;
    size_t off = 0;
    float* hA = (float*)(ws + off); off += (size_t)N * FDIM * 4;       // 51.2 MB
    float* hB = (float*)(ws + off); off += (size_t)N * FDIM * 4;       // 51.2 MB
    float* ssrc = (float*)(ws + off); off += (size_t)N * HEADS * 4;
    float* sdst = (float*)(ws + off); off += (size_t)N * HEADS * 4;
    int* rowstart = (int*)(ws + off); off += ((size_t)(N + 1) * 4 + 255) / 256 * 256;
    int* cursor = (int*)(ws + off); off += (size_t)N * 4;
    int* csr_src = (int*)(ws + off); off += (size_t)E * 4;
    float* pooled = (float*)(ws + off); off += (size_t)NGRAPHS * FDIM * 4;

    // ---- CSR build (per call; atomic fill order only perturbs fp rounding) ----
    hipMemsetAsync(cursor, 0, (size_t)N * 4, stream);
    k_hist<<<(E + 255) / 256, 256, 0, stream>>>(e_dst, E, cursor);
    k_scan<<<1, 1024, 0, stream>>>(cursor, N, rowstart);
    hipMemsetAsync(cursor, 0, (size_t)N * 4, stream);
    k_scatter<<<(E + 255) / 256, 256, 0, stream>>>(e_src, e_dst, E, rowstart, cursor, csr_src);

    // ---- 3 GAT layers ----
    const float* cur_in = x;
    int K = INCH;
    for (int l = 0; l < 3; ++l) {
        dim3 ggrid((N + 63) / 64, FDIM / 64);
        k_gemm<<<ggrid, 256, 0, stream>>>(cur_in, W[l], hA, N, K);
        k_scores<<<(N + 3) / 4, 256, 0, stream>>>(hA, asrc[l], adst[l], ssrc, sdst, N);
        k_aggregate<<<N, 256, 0, stream>>>(hA, ssrc, sdst, rowstart, csr_src, bias[l], hB, N);
        cur_in = hB;
        K = FDIM;
    }

    // ---- pool + classifier ----
    hipMemsetAsync(pooled, 0, (size_t)NGRAPHS * FDIM * 4, stream);
    k_pool<<<(N + 127) / 128, 256, 0, stream>>>(hB, batch, pooled, N);
    k_final<<<4, 256, 0, stream>>>(pooled, Wc, bc, (float*)d_out);
}

// Round 2
// 601.309 us; speedup vs baseline: 1.8538x; 1.8538x over previous
//
#include <hip/hip_runtime.h>
#include <hip/hip_bf16.h>

#define NNODES 50000
#define NEDGES 500000
#define INCH 128
#define HID 64
#define HEADS 4
#define FDIM 256
#define NGRAPHS 64
#define OUTCH 16
#define NEG_SLOPE 0.2f

#define BM 64
#define BN 256
#define BK 32
#define APITCH 40   // LDS row pitch in bf16 elems (80 B) -> conflict-free-ish

typedef float f32x4 __attribute__((ext_vector_type(4)));
typedef __bf16 bf16x8 __attribute__((ext_vector_type(8)));
typedef unsigned short u16x8 __attribute__((ext_vector_type(8)));

__device__ inline unsigned short f2bf_rne(float x) {
    unsigned int u = __float_as_uint(x);
    unsigned int r = (u + 0x7FFFu + ((u >> 16) & 1u)) >> 16;
    return (unsigned short)r;
}
__device__ inline void split2(float x, unsigned short& h, unsigned short& l) {
    h = f2bf_rne(x);
    float hf = __uint_as_float(((unsigned int)h) << 16);
    l = f2bf_rne(x - hf);
}

// ---------------- CSR build ----------------

__global__ void k_hist(const int* __restrict__ dst, int E, int* __restrict__ counts) {
    int i = blockIdx.x * blockDim.x + threadIdx.x;
    if (i < E) atomicAdd(&counts[dst[i]], 1);
}

__global__ __launch_bounds__(1024) void k_scan(const int* __restrict__ counts, int N,
                                               int* __restrict__ rowstart) {
    __shared__ int sums[1024];
    int t = threadIdx.x;
    const int CH = (N + 1023) / 1024;
    int base = t * CH;
    int s = 0;
    for (int i = 0; i < CH; ++i) {
        int idx = base + i;
        if (idx < N) s += counts[idx];
    }
    sums[t] = s;
    __syncthreads();
    for (int off = 1; off < 1024; off <<= 1) {
        int v = (t >= off) ? sums[t - off] : 0;
        __syncthreads();
        sums[t] += v;
        __syncthreads();
    }
    int prefix = (t == 0) ? 0 : sums[t - 1];
    if (t == 0) rowstart[0] = 0;
    for (int i = 0; i < CH; ++i) {
        int idx = base + i;
        if (idx < N) {
            prefix += counts[idx];
            rowstart[idx + 1] = prefix;
        }
    }
}

__global__ void k_scatter(const int* __restrict__ src, const int* __restrict__ dst, int E,
                          const int* __restrict__ rowstart, int* __restrict__ cursor,
                          int* __restrict__ csr_src) {
    int i = blockIdx.x * blockDim.x + threadIdx.x;
    if (i < E) {
        int d = dst[i];
        int p = atomicAdd(&cursor[d], 1);
        csr_src[rowstart[d] + p] = src[i];
    }
}

// ---------------- W transpose + hi/lo split: W[K][256] -> Wt_{hi,lo}[256][K] ----------------

__global__ void k_wdecomp(const float* __restrict__ W, unsigned short* __restrict__ Wth,
                          unsigned short* __restrict__ Wtl, int K) {
    int i = blockIdx.x * 256 + threadIdx.x;
    if (i >= K * 256) return;
    int k = i >> 8, n = i & 255;
    unsigned short h, l;
    split2(W[i], h, l);
    Wth[n * K + k] = h;
    Wtl[n * K + k] = l;
}

// ---------------- MFMA GEMM (split-bf16) + fused attention-score epilogue ----------------
// H[M][256] = A[M][K] (fp32, split on the fly) @ W[K][256] (pre-split, transposed)
// ssrc[r][head] = sum_c H[r][head*64+c]*asrc[head][c]  (wave wv owns head wv's 64 cols)

__global__ __launch_bounds__(256) void k_gemm_mfma(
    const float* __restrict__ A, const unsigned short* __restrict__ Bh,
    const unsigned short* __restrict__ Bl, const float* __restrict__ av,
    const float* __restrict__ dv, float* __restrict__ H,
    float* __restrict__ ssrcO, float* __restrict__ sdstO, int M, int K) {
    __shared__ unsigned short Ah[BM * APITCH];
    __shared__ unsigned short Al[BM * APITCH];
    __shared__ unsigned short Bhs[BN * APITCH];
    __shared__ unsigned short Bls[BN * APITCH];

    const int t = threadIdx.x;
    const int row0 = blockIdx.x * BM;
    const int wv = t >> 6, ln = t & 63, lr = ln & 15, lk = ln >> 4;

    const int arow = t >> 2, akb = t & 3;  // A staging: one 16B chunk each
    const int gr = min(row0 + arow, M - 1);

    f32x4 acc[4][4] = {};

    for (int k0 = 0; k0 < K; k0 += BK) {
        // ---- stage A (fp32 -> hi/lo bf16 on the fly) ----
        {
            const float* ap = A + (size_t)gr * K + k0 + akb * 8;
            float4 f0 = *(const float4*)(ap);
            float4 f1 = *(const float4*)(ap + 4);
            u16x8 hv, lv;
            float xs[8] = {f0.x, f0.y, f0.z, f0.w, f1.x, f1.y, f1.z, f1.w};
#pragma unroll
            for (int j = 0; j < 8; ++j) {
                unsigned short hh, ll;
                split2(xs[j], hh, ll);
                hv[j] = hh; lv[j] = ll;
            }
            *(u16x8*)&Ah[arow * APITCH + akb * 8] = hv;
            *(u16x8*)&Al[arow * APITCH + akb * 8] = lv;
        }
        // ---- stage B (pre-split planes) ----
#pragma unroll
        for (int i = 0; i < 4; ++i) {
            int crow = (t >> 2) + i * 64;
            int kb = t & 3;
            *(u16x8*)&Bhs[crow * APITCH + kb * 8] =
                *(const u16x8*)(Bh + (size_t)crow * K + k0 + kb * 8);
            *(u16x8*)&Bls[crow * APITCH + kb * 8] =
                *(const u16x8*)(Bl + (size_t)crow * K + k0 + kb * 8);
        }
        __syncthreads();

        bf16x8 ah[4], al[4];
#pragma unroll
        for (int mi = 0; mi < 4; ++mi) {
            ah[mi] = *(const bf16x8*)&Ah[(mi * 16 + lr) * APITCH + lk * 8];
            al[mi] = *(const bf16x8*)&Al[(mi * 16 + lr) * APITCH + lk * 8];
        }
#pragma unroll
        for (int ni = 0; ni < 4; ++ni) {
            int brow = wv * 64 + ni * 16 + lr;
            bf16x8 bh = *(const bf16x8*)&Bhs[brow * APITCH + lk * 8];
            bf16x8 bl = *(const bf16x8*)&Bls[brow * APITCH + lk * 8];
#pragma unroll
            for (int mi = 0; mi < 4; ++mi) {
                acc[mi][ni] = __builtin_amdgcn_mfma_f32_16x16x32_bf16(ah[mi], bh, acc[mi][ni], 0, 0, 0);
                acc[mi][ni] = __builtin_amdgcn_mfma_f32_16x16x32_bf16(ah[mi], bl, acc[mi][ni], 0, 0, 0);
                acc[mi][ni] = __builtin_amdgcn_mfma_f32_16x16x32_bf16(al[mi], bh, acc[mi][ni], 0, 0, 0);
            }
        }
        __syncthreads();
    }

    // ---- epilogue: store H + fused score partials ----
    float ps[4][4] = {}, pd[4][4] = {};
#pragma unroll
    for (int ni = 0; ni < 4; ++ni) {
        int col = wv * 64 + ni * 16 + lr;
        float a_s = av[col], a_d = dv[col];
#pragma unroll
        for (int mi = 0; mi < 4; ++mi) {
            f32x4 v = acc[mi][ni];
            int r = row0 + mi * 16 + lk * 4;
#pragma unroll
            for (int j = 0; j < 4; ++j) {
                if (r + j < M) H[(size_t)(r + j) * FDIM + col] = v[j];
                ps[mi][j] += v[j] * a_s;
                pd[mi][j] += v[j] * a_d;
            }
        }
    }
#pragma unroll
    for (int mi = 0; mi < 4; ++mi) {
#pragma unroll
        for (int j = 0; j < 4; ++j) {
            float s = ps[mi][j], q = pd[mi][j];
            s += __shfl_xor(s, 1); s += __shfl_xor(s, 2);
            s += __shfl_xor(s, 4); s += __shfl_xor(s, 8);
            q += __shfl_xor(q, 1); q += __shfl_xor(q, 2);
            q += __shfl_xor(q, 4); q += __shfl_xor(q, 8);
            if (lr == 0) {
                int r = row0 + mi * 16 + lk * 4 + j;
                if (r < M) {
                    ssrcO[r * HEADS + wv] = s;
                    sdstO[r * HEADS + wv] = q;
                }
            }
        }
    }
}

// ---------------- flash softmax + aggregation: one wave per node, float4 lanes ----------------

__global__ __launch_bounds__(256) void k_aggregate(const float* __restrict__ h,
                                                   const float* __restrict__ ssrc,
                                                   const float* __restrict__ sdst,
                                                   const int* __restrict__ rowstart,
                                                   const int* __restrict__ csr_src,
                                                   const float* __restrict__ b,
                                                   float* __restrict__ out, int N) {
    int wv = threadIdx.x >> 6, ln = threadIdx.x & 63;
    int n = blockIdx.x * 4 + wv;
    if (n >= N) return;
    int head = ln >> 4;
    int fo = head * 64 + (ln & 15) * 4;
    float sd = sdst[n * HEADS + head];
    float e = ssrc[n * HEADS + head] + sd;
    e = (e > 0.f) ? e : NEG_SLOPE * e;
    float m = e, d = 1.0f;
    float4 acc = *(const float4*)&h[(size_t)n * FDIM + fo];
    int r0 = rowstart[n], r1 = rowstart[n + 1];
    for (int r = r0; r < r1; ++r) {
        int s = csr_src[r];
        float sc = ssrc[s * HEADS + head] + sd;
        sc = (sc > 0.f) ? sc : NEG_SLOPE * sc;
        float4 hv = *(const float4*)&h[(size_t)s * FDIM + fo];
        float mn = fmaxf(m, sc);
        float wa = __expf(m - mn), wn = __expf(sc - mn);
        acc.x = acc.x * wa + hv.x * wn;
        acc.y = acc.y * wa + hv.y * wn;
        acc.z = acc.z * wa + hv.z * wn;
        acc.w = acc.w * wa + hv.w * wn;
        d = d * wa + wn;
        m = mn;
    }
    float inv = 1.0f / d;
    float4 bv = *(const float4*)&b[fo];
    float4 o;
    o.x = fmaxf(acc.x * inv + bv.x, 0.f);
    o.y = fmaxf(acc.y * inv + bv.y, 0.f);
    o.z = fmaxf(acc.z * inv + bv.z, 0.f);
    o.w = fmaxf(acc.w * inv + bv.w, 0.f);
    *(float4*)&out[(size_t)n * FDIM + fo] = o;
}

// ---------------- pooling (batch sorted) ----------------

__global__ __launch_bounds__(256) void k_pool(const float* __restrict__ h,
                                              const int* __restrict__ batch,
                                              float* __restrict__ pooled, int N) {
    int f = threadIdx.x;
    int n0 = blockIdx.x * 128;
    if (n0 >= N) return;
    int n1 = min(n0 + 128, N);
    int g = batch[n0];
    float run = 0.f;
    for (int n = n0; n < n1; ++n) {
        int gn = batch[n];
        if (gn != g) {
            atomicAdd(&pooled[g * FDIM + f], run);
            run = 0.f;
            g = gn;
        }
        run += h[(size_t)n * FDIM + f];
    }
    atomicAdd(&pooled[g * FDIM + f], run);
}

// ---------------- final classifier ----------------

__global__ __launch_bounds__(256) void k_final(const float* __restrict__ pooled,
                                               const float* __restrict__ Wc,
                                               const float* __restrict__ bc,
                                               float* __restrict__ out) {
    int tid = blockIdx.x * 256 + threadIdx.x;  // 0..1023
    int g = tid >> 4, o = tid & 15;
    float s = bc[o];
    for (int k = 0; k < FDIM; ++k) s += pooled[g * FDIM + k] * Wc[k * OUTCH + o];
    out[g * OUTCH + o] = s;
}

// ---------------- launch ----------------

extern "C" void kernel_launch(void* const* d_in, const int* in_sizes, int n_in,
                              void* d_out, int out_size, void* d_ws, size_t ws_size,
                              hipStream_t stream) {
    const float* x = (const float*)d_in[0];
    const int* edge_index = (const int*)d_in[2];
    const int* batch = (const int*)d_in[3];
    const float* W[3]    = {(const float*)d_in[4], (const float*)d_in[8],  (const float*)d_in[12]};
    const float* asrc[3] = {(const float*)d_in[5], (const float*)d_in[9],  (const float*)d_in[13]};
    const float* adst[3] = {(const float*)d_in[6], (const float*)d_in[10], (const float*)d_in[14]};
    const float* bias[3] = {(const float*)d_in[7], (const float*)d_in[11], (const float*)d_in[15]};
    const float* Wc = (const float*)d_in[16];
    const float* bc = (const float*)d_in[17];

    const int N = in_sizes[3];
    const int E = in_sizes[2] / 2;
    const int* e_src = edge_index;
    const int* e_dst = edge_index + E;

    char* ws = (char*)d_ws;
    size_t off = 0;
    float* h = (float*)(ws + off);   off += (size_t)N * FDIM * 4;
    float* outb = (float*)(ws + off); off += (size_t)N * FDIM * 4;
    float* ssrc = (float*)(ws + off); off += (size_t)N * HEADS * 4;
    float* sdst = (float*)(ws + off); off += (size_t)N * HEADS * 4;
    int* rowstart = (int*)(ws + off); off += ((size_t)(N + 1) * 4 + 255) / 256 * 256;
    int* cursor = (int*)(ws + off); off += (size_t)N * 4;
    int* csr_src = (int*)(ws + off); off += (size_t)E * 4;
    float* pooled = (float*)(ws + off); off += (size_t)NGRAPHS * FDIM * 4;
    unsigned short* Wth[3];
    unsigned short* Wtl[3];
    int Ks[3] = {INCH, FDIM, FDIM};
    for (int l = 0; l < 3; ++l) {
        Wth[l] = (unsigned short*)(ws + off); off += (size_t)256 * Ks[l] * 2;
        Wtl[l] = (unsigned short*)(ws + off); off += (size_t)256 * Ks[l] * 2;
    }

    // ---- CSR build ----
    hipMemsetAsync(cursor, 0, (size_t)N * 4, stream);
    k_hist<<<(E + 255) / 256, 256, 0, stream>>>(e_dst, E, cursor);
    k_scan<<<1, 1024, 0, stream>>>(cursor, N, rowstart);
    hipMemsetAsync(cursor, 0, (size_t)N * 4, stream);
    k_scatter<<<(E + 255) / 256, 256, 0, stream>>>(e_src, e_dst, E, rowstart, cursor, csr_src);

    // ---- weight pre-split ----
    for (int l = 0; l < 3; ++l)
        k_wdecomp<<<(Ks[l] * 256 + 255) / 256, 256, 0, stream>>>(W[l], Wth[l], Wtl[l], Ks[l]);

    // ---- 3 GAT layers ----
    const float* cur_in = x;
    for (int l = 0; l < 3; ++l) {
        int K = Ks[l];
        k_gemm_mfma<<<(N + BM - 1) / BM, 256, 0, stream>>>(cur_in, Wth[l], Wtl[l], asrc[l],
                                                           adst[l], h, ssrc, sdst, N, K);
        k_aggregate<<<(N + 3) / 4, 256, 0, stream>>>(h, ssrc, sdst, rowstart, csr_src,
                                                     bias[l], outb, N);
        cur_in = outb;
    }

    // ---- pool + classifier ----
    hipMemsetAsync(pooled, 0, (size_t)NGRAPHS * FDIM * 4, stream);
    k_pool<<<(N + 127) / 128, 256, 0, stream>>>(outb, batch, pooled, N);
    k_final<<<4, 256, 0, stream>>>(pooled, Wc, bc, (float*)d_out);
}

// Round 3
// 502.485 us; speedup vs baseline: 2.2184x; 1.1967x over previous
//
#include <hip/hip_runtime.h>
#include <hip/hip_bf16.h>

#define NNODES 50000
#define NEDGES 500000
#define INCH 128
#define HID 64
#define HEADS 4
#define FDIM 256
#define NGRAPHS 64
#define OUTCH 16
#define NEG_SLOPE 0.2f

#define BM 64
#define BN 256
#define BK 32
#define APITCH 40   // LDS row pitch in bf16 elems (80 B)

typedef float f32x4 __attribute__((ext_vector_type(4)));
typedef __bf16 bf16x8 __attribute__((ext_vector_type(8)));
typedef unsigned short u16x8 __attribute__((ext_vector_type(8)));

__device__ inline unsigned short f2bf_rne(float x) {
    unsigned int u = __float_as_uint(x);
    unsigned int r = (u + 0x7FFFu + ((u >> 16) & 1u)) >> 16;
    return (unsigned short)r;
}
__device__ inline void split2(float x, unsigned short& h, unsigned short& l) {
    h = f2bf_rne(x);
    float hf = __uint_as_float(((unsigned int)h) << 16);
    l = f2bf_rne(x - hf);
}

// ---------------- CSR build ----------------

__global__ void k_hist(const int* __restrict__ dst, int E, int* __restrict__ counts) {
    int i = blockIdx.x * blockDim.x + threadIdx.x;
    if (i < E) atomicAdd(&counts[dst[i]], 1);
}

// hierarchical scan: per-block sums, then per-block scan with on-the-fly block prefix
__global__ __launch_bounds__(256) void k_blocksum(const int* __restrict__ counts, int N,
                                                  int* __restrict__ bsum) {
    int idx = blockIdx.x * 256 + threadIdx.x;
    int v = (idx < N) ? counts[idx] : 0;
#pragma unroll
    for (int off = 32; off; off >>= 1) v += __shfl_xor(v, off);
    __shared__ int wsum[4];
    if ((threadIdx.x & 63) == 0) wsum[threadIdx.x >> 6] = v;
    __syncthreads();
    if (threadIdx.x == 0) bsum[blockIdx.x] = wsum[0] + wsum[1] + wsum[2] + wsum[3];
}

__global__ __launch_bounds__(256) void k_scanfinal(const int* __restrict__ counts,
                                                   const int* __restrict__ bsum, int N,
                                                   int* __restrict__ rowstart) {
    __shared__ int tmp[256];
    __shared__ int wsum[4];
    int t = threadIdx.x, b = blockIdx.x;
    // prefix over preceding blocks (bsum is tiny, L2-hot)
    int p = 0;
    for (int i = t; i < b; i += 256) p += bsum[i];
#pragma unroll
    for (int off = 32; off; off >>= 1) p += __shfl_xor(p, off);
    int idx = b * 256 + t;
    int v = (idx < N) ? counts[idx] : 0;
    tmp[t] = v;
    if ((t & 63) == 0) wsum[t >> 6] = p;
    __syncthreads();
    int bp = wsum[0] + wsum[1] + wsum[2] + wsum[3];
    // intra-block inclusive scan
    for (int off = 1; off < 256; off <<= 1) {
        int u = (t >= off) ? tmp[t - off] : 0;
        __syncthreads();
        tmp[t] += u;
        __syncthreads();
    }
    if (idx < N) rowstart[idx + 1] = bp + tmp[t];
    if (idx == 0) rowstart[0] = 0;
}

__global__ void k_scatter(const int* __restrict__ src, const int* __restrict__ dst, int E,
                          const int* __restrict__ rowstart, int* __restrict__ cursor,
                          int* __restrict__ csr_src) {
    int i = blockIdx.x * blockDim.x + threadIdx.x;
    if (i < E) {
        int d = dst[i];
        int p = atomicAdd(&cursor[d], 1);
        csr_src[rowstart[d] + p] = src[i];
    }
}

// ---------------- W transpose + hi/lo split ----------------

__global__ void k_wdecomp(const float* __restrict__ W, unsigned short* __restrict__ Wth,
                          unsigned short* __restrict__ Wtl, int K) {
    int i = blockIdx.x * 256 + threadIdx.x;
    if (i >= K * 256) return;
    int k = i >> 8, n = i & 255;
    unsigned short h, l;
    split2(W[i], h, l);
    Wth[n * K + k] = h;
    Wtl[n * K + k] = l;
}

// ---------------- MFMA GEMM (split-bf16) + fused attention-score epilogue ----------------

__global__ __launch_bounds__(256) void k_gemm_mfma(
    const float* __restrict__ A, const unsigned short* __restrict__ Bh,
    const unsigned short* __restrict__ Bl, const float* __restrict__ av,
    const float* __restrict__ dv, float* __restrict__ H,
    float* __restrict__ ssrcO, float* __restrict__ sdstO, int M, int K) {
    __shared__ unsigned short Ah[BM * APITCH];
    __shared__ unsigned short Al[BM * APITCH];
    __shared__ unsigned short Bhs[BN * APITCH];
    __shared__ unsigned short Bls[BN * APITCH];

    const int t = threadIdx.x;
    const int row0 = blockIdx.x * BM;
    const int wv = t >> 6, ln = t & 63, lr = ln & 15, lk = ln >> 4;

    const int arow = t >> 2, akb = t & 3;
    const int gr = min(row0 + arow, M - 1);

    f32x4 acc[4][4] = {};

    for (int k0 = 0; k0 < K; k0 += BK) {
        {
            const float* ap = A + (size_t)gr * K + k0 + akb * 8;
            float4 f0 = *(const float4*)(ap);
            float4 f1 = *(const float4*)(ap + 4);
            u16x8 hv, lv;
            float xs[8] = {f0.x, f0.y, f0.z, f0.w, f1.x, f1.y, f1.z, f1.w};
#pragma unroll
            for (int j = 0; j < 8; ++j) {
                unsigned short hh, ll;
                split2(xs[j], hh, ll);
                hv[j] = hh; lv[j] = ll;
            }
            *(u16x8*)&Ah[arow * APITCH + akb * 8] = hv;
            *(u16x8*)&Al[arow * APITCH + akb * 8] = lv;
        }
#pragma unroll
        for (int i = 0; i < 4; ++i) {
            int crow = (t >> 2) + i * 64;
            int kb = t & 3;
            *(u16x8*)&Bhs[crow * APITCH + kb * 8] =
                *(const u16x8*)(Bh + (size_t)crow * K + k0 + kb * 8);
            *(u16x8*)&Bls[crow * APITCH + kb * 8] =
                *(const u16x8*)(Bl + (size_t)crow * K + k0 + kb * 8);
        }
        __syncthreads();

        bf16x8 ah[4], al[4];
#pragma unroll
        for (int mi = 0; mi < 4; ++mi) {
            ah[mi] = *(const bf16x8*)&Ah[(mi * 16 + lr) * APITCH + lk * 8];
            al[mi] = *(const bf16x8*)&Al[(mi * 16 + lr) * APITCH + lk * 8];
        }
#pragma unroll
        for (int ni = 0; ni < 4; ++ni) {
            int brow = wv * 64 + ni * 16 + lr;
            bf16x8 bh = *(const bf16x8*)&Bhs[brow * APITCH + lk * 8];
            bf16x8 bl = *(const bf16x8*)&Bls[brow * APITCH + lk * 8];
#pragma unroll
            for (int mi = 0; mi < 4; ++mi) {
                acc[mi][ni] = __builtin_amdgcn_mfma_f32_16x16x32_bf16(ah[mi], bh, acc[mi][ni], 0, 0, 0);
                acc[mi][ni] = __builtin_amdgcn_mfma_f32_16x16x32_bf16(ah[mi], bl, acc[mi][ni], 0, 0, 0);
                acc[mi][ni] = __builtin_amdgcn_mfma_f32_16x16x32_bf16(al[mi], bh, acc[mi][ni], 0, 0, 0);
            }
        }
        __syncthreads();
    }

    float ps[4][4] = {}, pd[4][4] = {};
#pragma unroll
    for (int ni = 0; ni < 4; ++ni) {
        int col = wv * 64 + ni * 16 + lr;
        float a_s = av[col], a_d = dv[col];
#pragma unroll
        for (int mi = 0; mi < 4; ++mi) {
            f32x4 v = acc[mi][ni];
            int r = row0 + mi * 16 + lk * 4;
#pragma unroll
            for (int j = 0; j < 4; ++j) {
                if (r + j < M) H[(size_t)(r + j) * FDIM + col] = v[j];
                ps[mi][j] += v[j] * a_s;
                pd[mi][j] += v[j] * a_d;
            }
        }
    }
#pragma unroll
    for (int mi = 0; mi < 4; ++mi) {
#pragma unroll
        for (int j = 0; j < 4; ++j) {
            float s = ps[mi][j], q = pd[mi][j];
            s += __shfl_xor(s, 1); s += __shfl_xor(s, 2);
            s += __shfl_xor(s, 4); s += __shfl_xor(s, 8);
            q += __shfl_xor(q, 1); q += __shfl_xor(q, 2);
            q += __shfl_xor(q, 4); q += __shfl_xor(q, 8);
            if (lr == 0) {
                int r = row0 + mi * 16 + lk * 4 + j;
                if (r < M) {
                    ssrcO[r * HEADS + wv] = s;
                    sdstO[r * HEADS + wv] = q;
                }
            }
        }
    }
}

// ---------------- flash softmax + aggregation: one wave per node, 2-way unrolled ----------------

__global__ __launch_bounds__(256) void k_aggregate(const float* __restrict__ h,
                                                   const float* __restrict__ ssrc,
                                                   const float* __restrict__ sdst,
                                                   const int* __restrict__ rowstart,
                                                   const int* __restrict__ csr_src,
                                                   const float* __restrict__ b,
                                                   float* __restrict__ out, int N) {
    int wv = threadIdx.x >> 6, ln = threadIdx.x & 63;
    int n = blockIdx.x * 4 + wv;
    if (n >= N) return;
    int head = ln >> 4;
    int fo = head * 64 + (ln & 15) * 4;
    float sd = sdst[n * HEADS + head];
    float e = ssrc[n * HEADS + head] + sd;
    e = (e > 0.f) ? e : NEG_SLOPE * e;
    float m = e, d = 1.0f;
    float4 acc = *(const float4*)&h[(size_t)n * FDIM + fo];
    int r0 = rowstart[n], r1 = rowstart[n + 1];
    int r = r0;
    for (; r + 1 < r1; r += 2) {
        int s0 = csr_src[r], s1 = csr_src[r + 1];
        float sc0 = ssrc[s0 * HEADS + head] + sd;
        float sc1 = ssrc[s1 * HEADS + head] + sd;
        sc0 = (sc0 > 0.f) ? sc0 : NEG_SLOPE * sc0;
        sc1 = (sc1 > 0.f) ? sc1 : NEG_SLOPE * sc1;
        float4 h0 = *(const float4*)&h[(size_t)s0 * FDIM + fo];
        float4 h1 = *(const float4*)&h[(size_t)s1 * FDIM + fo];
        float mn = fmaxf(m, fmaxf(sc0, sc1));
        float wa = __expf(m - mn), w0 = __expf(sc0 - mn), w1 = __expf(sc1 - mn);
        acc.x = acc.x * wa + h0.x * w0 + h1.x * w1;
        acc.y = acc.y * wa + h0.y * w0 + h1.y * w1;
        acc.z = acc.z * wa + h0.z * w0 + h1.z * w1;
        acc.w = acc.w * wa + h0.w * w0 + h1.w * w1;
        d = d * wa + w0 + w1;
        m = mn;
    }
    if (r < r1) {
        int s0 = csr_src[r];
        float sc = ssrc[s0 * HEADS + head] + sd;
        sc = (sc > 0.f) ? sc : NEG_SLOPE * sc;
        float4 hv = *(const float4*)&h[(size_t)s0 * FDIM + fo];
        float mn = fmaxf(m, sc);
        float wa = __expf(m - mn), wn = __expf(sc - mn);
        acc.x = acc.x * wa + hv.x * wn;
        acc.y = acc.y * wa + hv.y * wn;
        acc.z = acc.z * wa + hv.z * wn;
        acc.w = acc.w * wa + hv.w * wn;
        d = d * wa + wn;
        m = mn;
    }
    float inv = 1.0f / d;
    float4 bv = *(const float4*)&b[fo];
    float4 o;
    o.x = fmaxf(acc.x * inv + bv.x, 0.f);
    o.y = fmaxf(acc.y * inv + bv.y, 0.f);
    o.z = fmaxf(acc.z * inv + bv.z, 0.f);
    o.w = fmaxf(acc.w * inv + bv.w, 0.f);
    *(float4*)&out[(size_t)n * FDIM + fo] = o;
}

// ---------------- pooling (batch sorted) ----------------

__global__ __launch_bounds__(256) void k_pool(const float* __restrict__ h,
                                              const int* __restrict__ batch,
                                              float* __restrict__ pooled, int N) {
    int f = threadIdx.x;
    int n0 = blockIdx.x * 128;
    if (n0 >= N) return;
    int n1 = min(n0 + 128, N);
    int g = batch[n0];
    float run = 0.f;
    for (int n = n0; n < n1; ++n) {
        int gn = batch[n];
        if (gn != g) {
            atomicAdd(&pooled[g * FDIM + f], run);
            run = 0.f;
            g = gn;
        }
        run += h[(size_t)n * FDIM + f];
    }
    atomicAdd(&pooled[g * FDIM + f], run);
}

// ---------------- final classifier ----------------

__global__ __launch_bounds__(256) void k_final(const float* __restrict__ pooled,
                                               const float* __restrict__ Wc,
                                               const float* __restrict__ bc,
                                               float* __restrict__ out) {
    int tid = blockIdx.x * 256 + threadIdx.x;
    int g = tid >> 4, o = tid & 15;
    float s = bc[o];
    for (int k = 0; k < FDIM; ++k) s += pooled[g * FDIM + k] * Wc[k * OUTCH + o];
    out[g * OUTCH + o] = s;
}

// ---------------- launch ----------------

extern "C" void kernel_launch(void* const* d_in, const int* in_sizes, int n_in,
                              void* d_out, int out_size, void* d_ws, size_t ws_size,
                              hipStream_t stream) {
    const float* x = (const float*)d_in[0];
    const int* edge_index = (const int*)d_in[2];
    const int* batch = (const int*)d_in[3];
    const float* W[3]    = {(const float*)d_in[4], (const float*)d_in[8],  (const float*)d_in[12]};
    const float* asrc[3] = {(const float*)d_in[5], (const float*)d_in[9],  (const float*)d_in[13]};
    const float* adst[3] = {(const float*)d_in[6], (const float*)d_in[10], (const float*)d_in[14]};
    const float* bias[3] = {(const float*)d_in[7], (const float*)d_in[11], (const float*)d_in[15]};
    const float* Wc = (const float*)d_in[16];
    const float* bc = (const float*)d_in[17];

    const int N = in_sizes[3];
    const int E = in_sizes[2] / 2;
    const int* e_src = edge_index;
    const int* e_dst = edge_index + E;

    char* ws = (char*)d_ws;
    size_t off = 0;
    float* h = (float*)(ws + off);   off += (size_t)N * FDIM * 4;
    float* outb = (float*)(ws + off); off += (size_t)N * FDIM * 4;
    float* ssrc = (float*)(ws + off); off += (size_t)N * HEADS * 4;
    float* sdst = (float*)(ws + off); off += (size_t)N * HEADS * 4;
    int* rowstart = (int*)(ws + off); off += ((size_t)(N + 1) * 4 + 255) / 256 * 256;
    int* cursor = (int*)(ws + off); off += (size_t)N * 4;
    int* csr_src = (int*)(ws + off); off += (size_t)E * 4;
    float* pooled = (float*)(ws + off); off += (size_t)NGRAPHS * FDIM * 4;
    int* bsum = (int*)(ws + off); off += ((size_t)((N + 255) / 256) * 4 + 255) / 256 * 256;
    unsigned short* Wth[3];
    unsigned short* Wtl[3];
    int Ks[3] = {INCH, FDIM, FDIM};
    for (int l = 0; l < 3; ++l) {
        Wth[l] = (unsigned short*)(ws + off); off += (size_t)256 * Ks[l] * 2;
        Wtl[l] = (unsigned short*)(ws + off); off += (size_t)256 * Ks[l] * 2;
    }

    const int nb = (N + 255) / 256;

    // ---- CSR build ----
    hipMemsetAsync(cursor, 0, (size_t)N * 4, stream);
    k_hist<<<(E + 255) / 256, 256, 0, stream>>>(e_dst, E, cursor);
    k_blocksum<<<nb, 256, 0, stream>>>(cursor, N, bsum);
    k_scanfinal<<<nb, 256, 0, stream>>>(cursor, bsum, N, rowstart);
    hipMemsetAsync(cursor, 0, (size_t)N * 4, stream);
    k_scatter<<<(E + 255) / 256, 256, 0, stream>>>(e_src, e_dst, E, rowstart, cursor, csr_src);

    // ---- weight pre-split ----
    for (int l = 0; l < 3; ++l)
        k_wdecomp<<<(Ks[l] * 256 + 255) / 256, 256, 0, stream>>>(W[l], Wth[l], Wtl[l], Ks[l]);

    // ---- 3 GAT layers ----
    const float* cur_in = x;
    for (int l = 0; l < 3; ++l) {
        int K = Ks[l];
        k_gemm_mfma<<<(N + BM - 1) / BM, 256, 0, stream>>>(cur_in, Wth[l], Wtl[l], asrc[l],
                                                           adst[l], h, ssrc, sdst, N, K);
        k_aggregate<<<(N + 3) / 4, 256, 0, stream>>>(h, ssrc, sdst, rowstart, csr_src,
                                                     bias[l], outb, N);
        cur_in = outb;
    }

    // ---- pool + classifier ----
    hipMemsetAsync(pooled, 0, (size_t)NGRAPHS * FDIM * 4, stream);
    k_pool<<<(N + 127) / 128, 256, 0, stream>>>(outb, batch, pooled, N);
    k_final<<<4, 256, 0, stream>>>(pooled, Wc, bc, (float*)d_out);
}

// Round 4
// 393.871 us; speedup vs baseline: 2.8301x; 1.2758x over previous
//
#include <hip/hip_runtime.h>
#include <hip/hip_bf16.h>

#define NNODES 50000
#define NEDGES 500000
#define INCH 128
#define HID 64
#define HEADS 4
#define FDIM 256
#define NGRAPHS 64
#define OUTCH 16
#define NEG_SLOPE 0.2f

#define BM 64
#define BN 256
#define BK 32
#define APITCH 40   // LDS row pitch in bf16 elems (80 B)

typedef float f32x4 __attribute__((ext_vector_type(4)));
typedef __bf16 bf16x8 __attribute__((ext_vector_type(8)));
typedef unsigned short u16x8 __attribute__((ext_vector_type(8)));

__device__ inline unsigned short f2bf_rne(float x) {
    unsigned int u = __float_as_uint(x);
    unsigned int r = (u + 0x7FFFu + ((u >> 16) & 1u)) >> 16;
    return (unsigned short)r;
}
__device__ inline float bf2f(unsigned short s) {
    return __uint_as_float(((unsigned int)s) << 16);
}
__device__ inline void split2(float x, unsigned short& h, unsigned short& l) {
    h = f2bf_rne(x);
    float hf = __uint_as_float(((unsigned int)h) << 16);
    l = f2bf_rne(x - hf);
}

// ---------------- CSR build ----------------

__global__ void k_hist(const int* __restrict__ dst, int E, int* __restrict__ counts) {
    int i = blockIdx.x * blockDim.x + threadIdx.x;
    if (i < E) atomicAdd(&counts[dst[i]], 1);
}

__global__ __launch_bounds__(256) void k_blocksum(const int* __restrict__ counts, int N,
                                                  int* __restrict__ bsum) {
    int idx = blockIdx.x * 256 + threadIdx.x;
    int v = (idx < N) ? counts[idx] : 0;
#pragma unroll
    for (int off = 32; off; off >>= 1) v += __shfl_xor(v, off);
    __shared__ int wsum[4];
    if ((threadIdx.x & 63) == 0) wsum[threadIdx.x >> 6] = v;
    __syncthreads();
    if (threadIdx.x == 0) bsum[blockIdx.x] = wsum[0] + wsum[1] + wsum[2] + wsum[3];
}

__global__ __launch_bounds__(256) void k_scanfinal(const int* __restrict__ counts,
                                                   const int* __restrict__ bsum, int N,
                                                   int* __restrict__ rowstart) {
    __shared__ int tmp[256];
    __shared__ int wsum[4];
    int t = threadIdx.x, b = blockIdx.x;
    int p = 0;
    for (int i = t; i < b; i += 256) p += bsum[i];
#pragma unroll
    for (int off = 32; off; off >>= 1) p += __shfl_xor(p, off);
    int idx = b * 256 + t;
    int v = (idx < N) ? counts[idx] : 0;
    tmp[t] = v;
    if ((t & 63) == 0) wsum[t >> 6] = p;
    __syncthreads();
    int bp = wsum[0] + wsum[1] + wsum[2] + wsum[3];
    for (int off = 1; off < 256; off <<= 1) {
        int u = (t >= off) ? tmp[t - off] : 0;
        __syncthreads();
        tmp[t] += u;
        __syncthreads();
    }
    if (idx < N) rowstart[idx + 1] = bp + tmp[t];
    if (idx == 0) rowstart[0] = 0;
}

__global__ void k_scatter(const int* __restrict__ src, const int* __restrict__ dst, int E,
                          const int* __restrict__ rowstart, int* __restrict__ cursor,
                          int* __restrict__ csr_src) {
    int i = blockIdx.x * blockDim.x + threadIdx.x;
    if (i < E) {
        int d = dst[i];
        int p = atomicAdd(&cursor[d], 1);
        csr_src[rowstart[d] + p] = src[i];
    }
}

// ---------------- W transpose + hi/lo split ----------------

__global__ void k_wdecomp(const float* __restrict__ W, unsigned short* __restrict__ Wth,
                          unsigned short* __restrict__ Wtl, int K) {
    int i = blockIdx.x * 256 + threadIdx.x;
    if (i >= K * 256) return;
    int k = i >> 8, n = i & 255;
    unsigned short h, l;
    split2(W[i], h, l);
    Wth[n * K + k] = h;
    Wtl[n * K + k] = l;
}

// ---------------- MFMA GEMM (split-bf16) + fused scores; H stored as bf16 ----------------

__global__ __launch_bounds__(256) void k_gemm_mfma(
    const float* __restrict__ A, const unsigned short* __restrict__ Bh,
    const unsigned short* __restrict__ Bl, const float* __restrict__ av,
    const float* __restrict__ dv, unsigned short* __restrict__ Hb16,
    float* __restrict__ ssrcO, float* __restrict__ sdstO, int M, int K) {
    __shared__ unsigned short Ah[BM * APITCH];
    __shared__ unsigned short Al[BM * APITCH];
    __shared__ unsigned short Bhs[BN * APITCH];
    __shared__ unsigned short Bls[BN * APITCH];

    const int t = threadIdx.x;
    const int row0 = blockIdx.x * BM;
    const int wv = t >> 6, ln = t & 63, lr = ln & 15, lk = ln >> 4;

    const int arow = t >> 2, akb = t & 3;
    const int gr = min(row0 + arow, M - 1);

    f32x4 acc[4][4] = {};

    for (int k0 = 0; k0 < K; k0 += BK) {
        {
            const float* ap = A + (size_t)gr * K + k0 + akb * 8;
            float4 f0 = *(const float4*)(ap);
            float4 f1 = *(const float4*)(ap + 4);
            u16x8 hv, lv;
            float xs[8] = {f0.x, f0.y, f0.z, f0.w, f1.x, f1.y, f1.z, f1.w};
#pragma unroll
            for (int j = 0; j < 8; ++j) {
                unsigned short hh, ll;
                split2(xs[j], hh, ll);
                hv[j] = hh; lv[j] = ll;
            }
            *(u16x8*)&Ah[arow * APITCH + akb * 8] = hv;
            *(u16x8*)&Al[arow * APITCH + akb * 8] = lv;
        }
#pragma unroll
        for (int i = 0; i < 4; ++i) {
            int crow = (t >> 2) + i * 64;
            int kb = t & 3;
            *(u16x8*)&Bhs[crow * APITCH + kb * 8] =
                *(const u16x8*)(Bh + (size_t)crow * K + k0 + kb * 8);
            *(u16x8*)&Bls[crow * APITCH + kb * 8] =
                *(const u16x8*)(Bl + (size_t)crow * K + k0 + kb * 8);
        }
        __syncthreads();

        bf16x8 ah[4], al[4];
#pragma unroll
        for (int mi = 0; mi < 4; ++mi) {
            ah[mi] = *(const bf16x8*)&Ah[(mi * 16 + lr) * APITCH + lk * 8];
            al[mi] = *(const bf16x8*)&Al[(mi * 16 + lr) * APITCH + lk * 8];
        }
#pragma unroll
        for (int ni = 0; ni < 4; ++ni) {
            int brow = wv * 64 + ni * 16 + lr;
            bf16x8 bh = *(const bf16x8*)&Bhs[brow * APITCH + lk * 8];
            bf16x8 bl = *(const bf16x8*)&Bls[brow * APITCH + lk * 8];
#pragma unroll
            for (int mi = 0; mi < 4; ++mi) {
                acc[mi][ni] = __builtin_amdgcn_mfma_f32_16x16x32_bf16(ah[mi], bh, acc[mi][ni], 0, 0, 0);
                acc[mi][ni] = __builtin_amdgcn_mfma_f32_16x16x32_bf16(ah[mi], bl, acc[mi][ni], 0, 0, 0);
                acc[mi][ni] = __builtin_amdgcn_mfma_f32_16x16x32_bf16(al[mi], bh, acc[mi][ni], 0, 0, 0);
            }
        }
        __syncthreads();
    }

    float ps[4][4] = {}, pd[4][4] = {};
#pragma unroll
    for (int ni = 0; ni < 4; ++ni) {
        int col = wv * 64 + ni * 16 + lr;
        float a_s = av[col], a_d = dv[col];
#pragma unroll
        for (int mi = 0; mi < 4; ++mi) {
            f32x4 v = acc[mi][ni];
            int r = row0 + mi * 16 + lk * 4;
#pragma unroll
            for (int j = 0; j < 4; ++j) {
                if (r + j < M) Hb16[(size_t)(r + j) * FDIM + col] = f2bf_rne(v[j]);
                ps[mi][j] += v[j] * a_s;
                pd[mi][j] += v[j] * a_d;
            }
        }
    }
#pragma unroll
    for (int mi = 0; mi < 4; ++mi) {
#pragma unroll
        for (int j = 0; j < 4; ++j) {
            float s = ps[mi][j], q = pd[mi][j];
            s += __shfl_xor(s, 1); s += __shfl_xor(s, 2);
            s += __shfl_xor(s, 4); s += __shfl_xor(s, 8);
            q += __shfl_xor(q, 1); q += __shfl_xor(q, 2);
            q += __shfl_xor(q, 4); q += __shfl_xor(q, 8);
            if (lr == 0) {
                int r = row0 + mi * 16 + lk * 4 + j;
                if (r < M) {
                    ssrcO[r * HEADS + wv] = s;
                    sdstO[r * HEADS + wv] = q;
                }
            }
        }
    }
}

// ---------------- flash softmax + aggregation: bf16 gathers, one wave per node ----------------

__global__ __launch_bounds__(256) void k_aggregate(const unsigned short* __restrict__ hb,
                                                   const float* __restrict__ ssrc,
                                                   const float* __restrict__ sdst,
                                                   const int* __restrict__ rowstart,
                                                   const int* __restrict__ csr_src,
                                                   const float* __restrict__ bias,
                                                   float* __restrict__ out, int N) {
    int wv = threadIdx.x >> 6, ln = threadIdx.x & 63;
    int n = blockIdx.x * 4 + wv;
    if (n >= N) return;
    int head = ln >> 4;
    int fo = head * 64 + (ln & 15) * 4;
    float sd = sdst[n * HEADS + head];
    float e = ssrc[n * HEADS + head] + sd;
    e = (e > 0.f) ? e : NEG_SLOPE * e;
    float m = e, d = 1.0f;
    ushort4 sv = *(const ushort4*)&hb[(size_t)n * FDIM + fo];
    float4 acc = make_float4(bf2f(sv.x), bf2f(sv.y), bf2f(sv.z), bf2f(sv.w));
    int r0 = rowstart[n], r1 = rowstart[n + 1];
    int r = r0;
    for (; r + 1 < r1; r += 2) {
        int s0 = csr_src[r], s1 = csr_src[r + 1];
        float sc0 = ssrc[s0 * HEADS + head] + sd;
        float sc1 = ssrc[s1 * HEADS + head] + sd;
        sc0 = (sc0 > 0.f) ? sc0 : NEG_SLOPE * sc0;
        sc1 = (sc1 > 0.f) ? sc1 : NEG_SLOPE * sc1;
        ushort4 u0 = *(const ushort4*)&hb[(size_t)s0 * FDIM + fo];
        ushort4 u1 = *(const ushort4*)&hb[(size_t)s1 * FDIM + fo];
        float mn = fmaxf(m, fmaxf(sc0, sc1));
        float wa = __expf(m - mn), w0 = __expf(sc0 - mn), w1 = __expf(sc1 - mn);
        acc.x = acc.x * wa + bf2f(u0.x) * w0 + bf2f(u1.x) * w1;
        acc.y = acc.y * wa + bf2f(u0.y) * w0 + bf2f(u1.y) * w1;
        acc.z = acc.z * wa + bf2f(u0.z) * w0 + bf2f(u1.z) * w1;
        acc.w = acc.w * wa + bf2f(u0.w) * w0 + bf2f(u1.w) * w1;
        d = d * wa + w0 + w1;
        m = mn;
    }
    if (r < r1) {
        int s0 = csr_src[r];
        float sc = ssrc[s0 * HEADS + head] + sd;
        sc = (sc > 0.f) ? sc : NEG_SLOPE * sc;
        ushort4 u0 = *(const ushort4*)&hb[(size_t)s0 * FDIM + fo];
        float mn = fmaxf(m, sc);
        float wa = __expf(m - mn), wn = __expf(sc - mn);
        acc.x = acc.x * wa + bf2f(u0.x) * wn;
        acc.y = acc.y * wa + bf2f(u0.y) * wn;
        acc.z = acc.z * wa + bf2f(u0.z) * wn;
        acc.w = acc.w * wa + bf2f(u0.w) * wn;
        d = d * wa + wn;
        m = mn;
    }
    float inv = 1.0f / d;
    float4 bv = *(const float4*)&bias[fo];
    float4 o;
    o.x = fmaxf(acc.x * inv + bv.x, 0.f);
    o.y = fmaxf(acc.y * inv + bv.y, 0.f);
    o.z = fmaxf(acc.z * inv + bv.z, 0.f);
    o.w = fmaxf(acc.w * inv + bv.w, 0.f);
    *(float4*)&out[(size_t)n * FDIM + fo] = o;
}

// ---------------- pooling (batch sorted) ----------------

__global__ __launch_bounds__(256) void k_pool(const float* __restrict__ h,
                                              const int* __restrict__ batch,
                                              float* __restrict__ pooled, int N) {
    int f = threadIdx.x;
    int n0 = blockIdx.x * 128;
    if (n0 >= N) return;
    int n1 = min(n0 + 128, N);
    int g = batch[n0];
    float run = 0.f;
    for (int n = n0; n < n1; ++n) {
        int gn = batch[n];
        if (gn != g) {
            atomicAdd(&pooled[g * FDIM + f], run);
            run = 0.f;
            g = gn;
        }
        run += h[(size_t)n * FDIM + f];
    }
    atomicAdd(&pooled[g * FDIM + f], run);
}

// ---------------- final classifier ----------------

__global__ __launch_bounds__(256) void k_final(const float* __restrict__ pooled,
                                               const float* __restrict__ Wc,
                                               const float* __restrict__ bc,
                                               float* __restrict__ out) {
    int tid = blockIdx.x * 256 + threadIdx.x;
    int g = tid >> 4, o = tid & 15;
    float s = bc[o];
    for (int k = 0; k < FDIM; ++k) s += pooled[g * FDIM + k] * Wc[k * OUTCH + o];
    out[g * OUTCH + o] = s;
}

// ---------------- launch ----------------

extern "C" void kernel_launch(void* const* d_in, const int* in_sizes, int n_in,
                              void* d_out, int out_size, void* d_ws, size_t ws_size,
                              hipStream_t stream) {
    const float* x = (const float*)d_in[0];
    const int* edge_index = (const int*)d_in[2];
    const int* batch = (const int*)d_in[3];
    const float* W[3]    = {(const float*)d_in[4], (const float*)d_in[8],  (const float*)d_in[12]};
    const float* asrc[3] = {(const float*)d_in[5], (const float*)d_in[9],  (const float*)d_in[13]};
    const float* adst[3] = {(const float*)d_in[6], (const float*)d_in[10], (const float*)d_in[14]};
    const float* bias[3] = {(const float*)d_in[7], (const float*)d_in[11], (const float*)d_in[15]};
    const float* Wc = (const float*)d_in[16];
    const float* bc = (const float*)d_in[17];

    const int N = in_sizes[3];
    const int E = in_sizes[2] / 2;
    const int* e_src = edge_index;
    const int* e_dst = edge_index + E;

    char* ws = (char*)d_ws;
    size_t off = 0;
    unsigned short* hb = (unsigned short*)(ws + off); off += (size_t)N * FDIM * 2;  // 25.6 MB
    float* outb = (float*)(ws + off); off += (size_t)N * FDIM * 4;                  // 51.2 MB
    float* ssrc = (float*)(ws + off); off += (size_t)N * HEADS * 4;
    float* sdst = (float*)(ws + off); off += (size_t)N * HEADS * 4;
    int* rowstart = (int*)(ws + off); off += ((size_t)(N + 1) * 4 + 255) / 256 * 256;
    int* cursor = (int*)(ws + off); off += (size_t)N * 4;
    int* csr_src = (int*)(ws + off); off += (size_t)E * 4;
    float* pooled = (float*)(ws + off); off += (size_t)NGRAPHS * FDIM * 4;
    int* bsum = (int*)(ws + off); off += ((size_t)((N + 255) / 256) * 4 + 255) / 256 * 256;
    unsigned short* Wth[3];
    unsigned short* Wtl[3];
    int Ks[3] = {INCH, FDIM, FDIM};
    for (int l = 0; l < 3; ++l) {
        Wth[l] = (unsigned short*)(ws + off); off += (size_t)256 * Ks[l] * 2;
        Wtl[l] = (unsigned short*)(ws + off); off += (size_t)256 * Ks[l] * 2;
    }

    const int nb = (N + 255) / 256;

    // ---- CSR build ----
    hipMemsetAsync(cursor, 0, (size_t)N * 4, stream);
    k_hist<<<(E + 255) / 256, 256, 0, stream>>>(e_dst, E, cursor);
    k_blocksum<<<nb, 256, 0, stream>>>(cursor, N, bsum);
    k_scanfinal<<<nb, 256, 0, stream>>>(cursor, bsum, N, rowstart);
    hipMemsetAsync(cursor, 0, (size_t)N * 4, stream);
    k_scatter<<<(E + 255) / 256, 256, 0, stream>>>(e_src, e_dst, E, rowstart, cursor, csr_src);

    // ---- weight pre-split ----
    for (int l = 0; l < 3; ++l)
        k_wdecomp<<<(Ks[l] * 256 + 255) / 256, 256, 0, stream>>>(W[l], Wth[l], Wtl[l], Ks[l]);

    // ---- 3 GAT layers ----
    const float* cur_in = x;
    for (int l = 0; l < 3; ++l) {
        int K = Ks[l];
        k_gemm_mfma<<<(N + BM - 1) / BM, 256, 0, stream>>>(cur_in, Wth[l], Wtl[l], asrc[l],
                                                           adst[l], hb, ssrc, sdst, N, K);
        k_aggregate<<<(N + 3) / 4, 256, 0, stream>>>(hb, ssrc, sdst, rowstart, csr_src,
                                                     bias[l], outb, N);
        cur_in = outb;
    }

    // ---- pool + classifier ----
    hipMemsetAsync(pooled, 0, (size_t)NGRAPHS * FDIM * 4, stream);
    k_pool<<<(N + 127) / 128, 256, 0, stream>>>(outb, batch, pooled, N);
    k_final<<<4, 256, 0, stream>>>(pooled, Wc, bc, (float*)d_out);
}

// Round 5
// 393.745 us; speedup vs baseline: 2.8310x; 1.0003x over previous
//
#include <hip/hip_runtime.h>
#include <hip/hip_bf16.h>

#define NNODES 50000
#define NEDGES 500000
#define INCH 128
#define HID 64
#define HEADS 4
#define FDIM 256
#define NGRAPHS 64
#define OUTCH 16
#define NEG_SLOPE 0.2f

#define BM 64
#define BN 256
#define BK 32

typedef float f32x4 __attribute__((ext_vector_type(4)));
typedef __bf16 bf16x8 __attribute__((ext_vector_type(8)));

__device__ inline unsigned short f2bf_rne(float x) {
    unsigned int u = __float_as_uint(x);
    unsigned int r = (u + 0x7FFFu + ((u >> 16) & 1u)) >> 16;
    return (unsigned short)r;
}
__device__ inline float bf2f(unsigned short s) {
    return __uint_as_float(((unsigned int)s) << 16);
}
__device__ inline void split2(float x, unsigned short& h, unsigned short& l) {
    h = f2bf_rne(x);
    float hf = __uint_as_float(((unsigned int)h) << 16);
    l = f2bf_rne(x - hf);
}
__device__ inline void gld_lds16(const void* g, void* l) {
    __builtin_amdgcn_global_load_lds((__attribute__((address_space(1))) void*)g,
                                     (__attribute__((address_space(3))) void*)l, 16, 0, 0);
}

// ---------------- CSR build ----------------

__global__ void k_hist(const int* __restrict__ dst, int E, int* __restrict__ counts) {
    int i = blockIdx.x * blockDim.x + threadIdx.x;
    if (i < E) atomicAdd(&counts[dst[i]], 1);
}

__global__ __launch_bounds__(256) void k_blocksum(const int* __restrict__ counts, int N,
                                                  int* __restrict__ bsum) {
    int idx = blockIdx.x * 256 + threadIdx.x;
    int v = (idx < N) ? counts[idx] : 0;
#pragma unroll
    for (int off = 32; off; off >>= 1) v += __shfl_xor(v, off);
    __shared__ int wsum[4];
    if ((threadIdx.x & 63) == 0) wsum[threadIdx.x >> 6] = v;
    __syncthreads();
    if (threadIdx.x == 0) bsum[blockIdx.x] = wsum[0] + wsum[1] + wsum[2] + wsum[3];
}

__global__ __launch_bounds__(256) void k_scanfinal(const int* __restrict__ counts,
                                                   const int* __restrict__ bsum, int N,
                                                   int* __restrict__ rowstart) {
    __shared__ int tmp[256];
    __shared__ int wsum[4];
    int t = threadIdx.x, b = blockIdx.x;
    int p = 0;
    for (int i = t; i < b; i += 256) p += bsum[i];
#pragma unroll
    for (int off = 32; off; off >>= 1) p += __shfl_xor(p, off);
    int idx = b * 256 + t;
    int v = (idx < N) ? counts[idx] : 0;
    tmp[t] = v;
    if ((t & 63) == 0) wsum[t >> 6] = p;
    __syncthreads();
    int bp = wsum[0] + wsum[1] + wsum[2] + wsum[3];
    for (int off = 1; off < 256; off <<= 1) {
        int u = (t >= off) ? tmp[t - off] : 0;
        __syncthreads();
        tmp[t] += u;
        __syncthreads();
    }
    if (idx < N) rowstart[idx + 1] = bp + tmp[t];
    if (idx == 0) rowstart[0] = 0;
}

__global__ void k_scatter(const int* __restrict__ src, const int* __restrict__ dst, int E,
                          const int* __restrict__ rowstart, int* __restrict__ cursor,
                          int* __restrict__ csr_src) {
    int i = blockIdx.x * blockDim.x + threadIdx.x;
    if (i < E) {
        int d = dst[i];
        int p = atomicAdd(&cursor[d], 1);
        csr_src[rowstart[d] + p] = src[i];
    }
}

// ---------------- weight transpose + hi/lo split: W[K][256] -> Wt[256][K] planes ----------------

__global__ void k_wdecomp(const float* __restrict__ W, unsigned short* __restrict__ Wth,
                          unsigned short* __restrict__ Wtl, int K) {
    int i = blockIdx.x * 256 + threadIdx.x;
    if (i >= K * 256) return;
    int k = i >> 8, n = i & 255;
    unsigned short h, l;
    split2(W[i], h, l);
    Wth[n * K + k] = h;
    Wtl[n * K + k] = l;
}

// ---------------- x -> hi/lo planes (row-major, same layout) ----------------

__global__ void k_adecomp(const float* __restrict__ X, unsigned short* __restrict__ Xh,
                          unsigned short* __restrict__ Xl, int total4) {
    int i = blockIdx.x * 256 + threadIdx.x;
    if (i >= total4) return;
    float4 v = ((const float4*)X)[i];
    ushort4 h, l;
    split2(v.x, h.x, l.x);
    split2(v.y, h.y, l.y);
    split2(v.z, h.z, l.z);
    split2(v.w, h.w, l.w);
    ((ushort4*)Xh)[i] = h;
    ((ushort4*)Xl)[i] = l;
}

// ---------------- MFMA GEMM on pre-split planes, global_load_lds staging ----------------
// H[M][256] = A[M][K] @ W[K][256], A/B given as bf16 hi/lo planes (B transposed [256][K]).
// LDS tiles are linear [rows][BK] with chunk-swizzle: stored chunk sc at row r holds
// logical chunk sc ^ ((r>>1)&3)  (16B chunks, 4 per row). Applied on the global source
// address at staging (gload_lds writes linearly) and on the ds_read address.

__global__ __launch_bounds__(256) void k_gemm_mfma(
    const unsigned short* __restrict__ Aph, const unsigned short* __restrict__ Apl,
    const unsigned short* __restrict__ Bph, const unsigned short* __restrict__ Bpl,
    const float* __restrict__ av, const float* __restrict__ dv,
    unsigned short* __restrict__ Hb16,
    float* __restrict__ ssrcO, float* __restrict__ sdstO, int M, int K) {
    __shared__ unsigned short sAh[BM * BK];
    __shared__ unsigned short sAl[BM * BK];
    __shared__ unsigned short sBh[BN * BK];
    __shared__ unsigned short sBl[BN * BK];

    const int t = threadIdx.x;
    const int row0 = blockIdx.x * BM;
    const int wv = t >> 6, ln = t & 63, lr = ln & 15, lk = ln >> 4;

    // A staging: lane ln of wave wv fills LDS bytes [wv*1024 + ln*16)
    const int ar = wv * 16 + (ln >> 2);                  // tile row
    const int alc = (ln & 3) ^ ((ar >> 1) & 3);          // logical chunk to fetch
    const size_t agoff = (size_t)min(row0 + ar, M - 1) * K + alc * 8;
    // fragment-read stored-chunk (same for all mi/ni since row%16 == lr)
    const int fsc = lk ^ ((lr >> 1) & 3);

    f32x4 acc[4][4] = {};

    for (int k0 = 0; k0 < K; k0 += BK) {
        gld_lds16(Aph + agoff + k0, &sAh[wv * 512]);
        gld_lds16(Apl + agoff + k0, &sAl[wv * 512]);
#pragma unroll
        for (int j = 0; j < 4; ++j) {
            int br = j * 64 + wv * 16 + (ln >> 2);
            int blc = (ln & 3) ^ ((br >> 1) & 3);
            size_t go = (size_t)br * K + k0 + blc * 8;
            gld_lds16(Bph + go, &sBh[j * 2048 + wv * 512]);
            gld_lds16(Bpl + go, &sBl[j * 2048 + wv * 512]);
        }
        __syncthreads();  // compiler drains vmcnt before barrier

        bf16x8 ah[4], al[4];
#pragma unroll
        for (int mi = 0; mi < 4; ++mi) {
            int r = mi * 16 + lr;
            ah[mi] = *(const bf16x8*)&sAh[r * 32 + fsc * 8];
            al[mi] = *(const bf16x8*)&sAl[r * 32 + fsc * 8];
        }
#pragma unroll
        for (int ni = 0; ni < 4; ++ni) {
            int br = wv * 64 + ni * 16 + lr;
            bf16x8 bh = *(const bf16x8*)&sBh[br * 32 + fsc * 8];
            bf16x8 bl = *(const bf16x8*)&sBl[br * 32 + fsc * 8];
#pragma unroll
            for (int mi = 0; mi < 4; ++mi) {
                acc[mi][ni] = __builtin_amdgcn_mfma_f32_16x16x32_bf16(ah[mi], bh, acc[mi][ni], 0, 0, 0);
                acc[mi][ni] = __builtin_amdgcn_mfma_f32_16x16x32_bf16(ah[mi], bl, acc[mi][ni], 0, 0, 0);
                acc[mi][ni] = __builtin_amdgcn_mfma_f32_16x16x32_bf16(al[mi], bh, acc[mi][ni], 0, 0, 0);
            }
        }
        __syncthreads();
    }

    // ---- epilogue: bf16 H store + fused score partials ----
    float ps[4][4] = {}, pd[4][4] = {};
#pragma unroll
    for (int ni = 0; ni < 4; ++ni) {
        int col = wv * 64 + ni * 16 + lr;
        float a_s = av[col], a_d = dv[col];
#pragma unroll
        for (int mi = 0; mi < 4; ++mi) {
            f32x4 v = acc[mi][ni];
            int r = row0 + mi * 16 + lk * 4;
#pragma unroll
            for (int j = 0; j < 4; ++j) {
                if (r + j < M) Hb16[(size_t)(r + j) * FDIM + col] = f2bf_rne(v[j]);
                ps[mi][j] += v[j] * a_s;
                pd[mi][j] += v[j] * a_d;
            }
        }
    }
#pragma unroll
    for (int mi = 0; mi < 4; ++mi) {
#pragma unroll
        for (int j = 0; j < 4; ++j) {
            float s = ps[mi][j], q = pd[mi][j];
            s += __shfl_xor(s, 1); s += __shfl_xor(s, 2);
            s += __shfl_xor(s, 4); s += __shfl_xor(s, 8);
            q += __shfl_xor(q, 1); q += __shfl_xor(q, 2);
            q += __shfl_xor(q, 4); q += __shfl_xor(q, 8);
            if (lr == 0) {
                int r = row0 + mi * 16 + lk * 4 + j;
                if (r < M) {
                    ssrcO[r * HEADS + wv] = s;
                    sdstO[r * HEADS + wv] = q;
                }
            }
        }
    }
}

// ---------------- flash softmax + aggregation: 4-way unrolled, writes hi/lo planes ----------------

__global__ __launch_bounds__(256) void k_aggregate(
    const unsigned short* __restrict__ hb,
    const float* __restrict__ ssrc, const float* __restrict__ sdst,
    const int* __restrict__ rowstart, const int* __restrict__ csr_src,
    const float* __restrict__ bias,
    unsigned short* __restrict__ oh, unsigned short* __restrict__ ol, int N) {
    int wv = threadIdx.x >> 6, ln = threadIdx.x & 63;
    int n = blockIdx.x * 4 + wv;
    if (n >= N) return;
    int head = ln >> 4;
    int fo = head * 64 + (ln & 15) * 4;
    float sd = sdst[n * HEADS + head];
    float e = ssrc[n * HEADS + head] + sd;
    e = (e > 0.f) ? e : NEG_SLOPE * e;
    float m = e, d = 1.0f;
    ushort4 sv = *(const ushort4*)&hb[(size_t)n * FDIM + fo];
    float4 acc = make_float4(bf2f(sv.x), bf2f(sv.y), bf2f(sv.z), bf2f(sv.w));
    int r0 = rowstart[n], r1 = rowstart[n + 1];
    int r = r0;
    for (; r + 3 < r1; r += 4) {
        int s0 = csr_src[r], s1 = csr_src[r + 1], s2 = csr_src[r + 2], s3 = csr_src[r + 3];
        ushort4 u0 = *(const ushort4*)&hb[(size_t)s0 * FDIM + fo];
        ushort4 u1 = *(const ushort4*)&hb[(size_t)s1 * FDIM + fo];
        ushort4 u2 = *(const ushort4*)&hb[(size_t)s2 * FDIM + fo];
        ushort4 u3 = *(const ushort4*)&hb[(size_t)s3 * FDIM + fo];
        float c0 = ssrc[s0 * HEADS + head] + sd;
        float c1 = ssrc[s1 * HEADS + head] + sd;
        float c2 = ssrc[s2 * HEADS + head] + sd;
        float c3 = ssrc[s3 * HEADS + head] + sd;
        c0 = (c0 > 0.f) ? c0 : NEG_SLOPE * c0;
        c1 = (c1 > 0.f) ? c1 : NEG_SLOPE * c1;
        c2 = (c2 > 0.f) ? c2 : NEG_SLOPE * c2;
        c3 = (c3 > 0.f) ? c3 : NEG_SLOPE * c3;
        float mn = fmaxf(m, fmaxf(fmaxf(c0, c1), fmaxf(c2, c3)));
        float wa = __expf(m - mn);
        float w0 = __expf(c0 - mn), w1 = __expf(c1 - mn);
        float w2 = __expf(c2 - mn), w3 = __expf(c3 - mn);
        acc.x = acc.x * wa + bf2f(u0.x) * w0 + bf2f(u1.x) * w1 + bf2f(u2.x) * w2 + bf2f(u3.x) * w3;
        acc.y = acc.y * wa + bf2f(u0.y) * w0 + bf2f(u1.y) * w1 + bf2f(u2.y) * w2 + bf2f(u3.y) * w3;
        acc.z = acc.z * wa + bf2f(u0.z) * w0 + bf2f(u1.z) * w1 + bf2f(u2.z) * w2 + bf2f(u3.z) * w3;
        acc.w = acc.w * wa + bf2f(u0.w) * w0 + bf2f(u1.w) * w1 + bf2f(u2.w) * w2 + bf2f(u3.w) * w3;
        d = d * wa + ((w0 + w1) + (w2 + w3));
        m = mn;
    }
    for (; r < r1; ++r) {
        int s0 = csr_src[r];
        float sc = ssrc[s0 * HEADS + head] + sd;
        sc = (sc > 0.f) ? sc : NEG_SLOPE * sc;
        ushort4 u0 = *(const ushort4*)&hb[(size_t)s0 * FDIM + fo];
        float mn = fmaxf(m, sc);
        float wa = __expf(m - mn), wn = __expf(sc - mn);
        acc.x = acc.x * wa + bf2f(u0.x) * wn;
        acc.y = acc.y * wa + bf2f(u0.y) * wn;
        acc.z = acc.z * wa + bf2f(u0.z) * wn;
        acc.w = acc.w * wa + bf2f(u0.w) * wn;
        d = d * wa + wn;
        m = mn;
    }
    float inv = 1.0f / d;
    float4 bv = *(const float4*)&bias[fo];
    float o0 = fmaxf(acc.x * inv + bv.x, 0.f);
    float o1 = fmaxf(acc.y * inv + bv.y, 0.f);
    float o2 = fmaxf(acc.z * inv + bv.z, 0.f);
    float o3 = fmaxf(acc.w * inv + bv.w, 0.f);
    ushort4 hh, ll;
    split2(o0, hh.x, ll.x);
    split2(o1, hh.y, ll.y);
    split2(o2, hh.z, ll.z);
    split2(o3, hh.w, ll.w);
    *(ushort4*)&oh[(size_t)n * FDIM + fo] = hh;
    *(ushort4*)&ol[(size_t)n * FDIM + fo] = ll;
}

// ---------------- pooling (batch sorted, reads hi/lo planes) ----------------

__global__ __launch_bounds__(256) void k_pool(const unsigned short* __restrict__ oh,
                                              const unsigned short* __restrict__ ol,
                                              const int* __restrict__ batch,
                                              float* __restrict__ pooled, int N) {
    int f = threadIdx.x;
    int n0 = blockIdx.x * 128;
    if (n0 >= N) return;
    int n1 = min(n0 + 128, N);
    int g = batch[n0];
    float run = 0.f;
    for (int n = n0; n < n1; ++n) {
        int gn = batch[n];
        if (gn != g) {
            atomicAdd(&pooled[g * FDIM + f], run);
            run = 0.f;
            g = gn;
        }
        run += bf2f(oh[(size_t)n * FDIM + f]) + bf2f(ol[(size_t)n * FDIM + f]);
    }
    atomicAdd(&pooled[g * FDIM + f], run);
}

// ---------------- final classifier ----------------

__global__ __launch_bounds__(256) void k_final(const float* __restrict__ pooled,
                                               const float* __restrict__ Wc,
                                               const float* __restrict__ bc,
                                               float* __restrict__ out) {
    int tid = blockIdx.x * 256 + threadIdx.x;
    int g = tid >> 4, o = tid & 15;
    float s = bc[o];
    for (int k = 0; k < FDIM; ++k) s += pooled[g * FDIM + k] * Wc[k * OUTCH + o];
    out[g * OUTCH + o] = s;
}

// ---------------- launch ----------------

extern "C" void kernel_launch(void* const* d_in, const int* in_sizes, int n_in,
                              void* d_out, int out_size, void* d_ws, size_t ws_size,
                              hipStream_t stream) {
    const float* x = (const float*)d_in[0];
    const int* edge_index = (const int*)d_in[2];
    const int* batch = (const int*)d_in[3];
    const float* W[3]    = {(const float*)d_in[4], (const float*)d_in[8],  (const float*)d_in[12]};
    const float* asrc[3] = {(const float*)d_in[5], (const float*)d_in[9],  (const float*)d_in[13]};
    const float* adst[3] = {(const float*)d_in[6], (const float*)d_in[10], (const float*)d_in[14]};
    const float* bias[3] = {(const float*)d_in[7], (const float*)d_in[11], (const float*)d_in[15]};
    const float* Wc = (const float*)d_in[16];
    const float* bc = (const float*)d_in[17];

    const int N = in_sizes[3];
    const int E = in_sizes[2] / 2;
    const int* e_src = edge_index;
    const int* e_dst = edge_index + E;

    char* ws = (char*)d_ws;
    size_t off = 0;
    unsigned short* hb = (unsigned short*)(ws + off); off += (size_t)N * FDIM * 2;   // 25.6 MB
    unsigned short* xh = (unsigned short*)(ws + off); off += (size_t)N * INCH * 2;   // 12.8 MB
    unsigned short* xl = (unsigned short*)(ws + off); off += (size_t)N * INCH * 2;
    unsigned short* P0h = (unsigned short*)(ws + off); off += (size_t)N * FDIM * 2;  // 25.6 MB
    unsigned short* P0l = (unsigned short*)(ws + off); off += (size_t)N * FDIM * 2;
    unsigned short* P1h = (unsigned short*)(ws + off); off += (size_t)N * FDIM * 2;
    unsigned short* P1l = (unsigned short*)(ws + off); off += (size_t)N * FDIM * 2;
    float* ssrc = (float*)(ws + off); off += (size_t)N * HEADS * 4;
    float* sdst = (float*)(ws + off); off += (size_t)N * HEADS * 4;
    int* rowstart = (int*)(ws + off); off += ((size_t)(N + 1) * 4 + 255) / 256 * 256;
    int* cursor = (int*)(ws + off); off += (size_t)N * 4;
    int* csr_src = (int*)(ws + off); off += (size_t)E * 4;
    float* pooled = (float*)(ws + off); off += (size_t)NGRAPHS * FDIM * 4;
    int* bsum = (int*)(ws + off); off += ((size_t)((N + 255) / 256) * 4 + 255) / 256 * 256;
    unsigned short* Wth[3];
    unsigned short* Wtl[3];
    int Ks[3] = {INCH, FDIM, FDIM};
    for (int l = 0; l < 3; ++l) {
        Wth[l] = (unsigned short*)(ws + off); off += (size_t)256 * Ks[l] * 2;
        Wtl[l] = (unsigned short*)(ws + off); off += (size_t)256 * Ks[l] * 2;
    }

    const int nb = (N + 255) / 256;

    // ---- CSR build ----
    hipMemsetAsync(cursor, 0, (size_t)N * 4, stream);
    k_hist<<<(E + 255) / 256, 256, 0, stream>>>(e_dst, E, cursor);
    k_blocksum<<<nb, 256, 0, stream>>>(cursor, N, bsum);
    k_scanfinal<<<nb, 256, 0, stream>>>(cursor, bsum, N, rowstart);
    hipMemsetAsync(cursor, 0, (size_t)N * 4, stream);
    k_scatter<<<(E + 255) / 256, 256, 0, stream>>>(e_src, e_dst, E, rowstart, cursor, csr_src);

    // ---- input + weight pre-split ----
    k_adecomp<<<((N * INCH / 4) + 255) / 256, 256, 0, stream>>>(x, xh, xl, N * INCH / 4);
    for (int l = 0; l < 3; ++l)
        k_wdecomp<<<(Ks[l] * 256 + 255) / 256, 256, 0, stream>>>(W[l], Wth[l], Wtl[l], Ks[l]);

    // ---- 3 GAT layers (plane ping-pong) ----
    const unsigned short* Ah = xh;
    const unsigned short* Al = xl;
    unsigned short* Oh[3] = {P0h, P1h, P0h};
    unsigned short* Ol[3] = {P0l, P1l, P0l};
    for (int l = 0; l < 3; ++l) {
        int K = Ks[l];
        k_gemm_mfma<<<(N + BM - 1) / BM, 256, 0, stream>>>(Ah, Al, Wth[l], Wtl[l], asrc[l],
                                                           adst[l], hb, ssrc, sdst, N, K);
        k_aggregate<<<(N + 3) / 4, 256, 0, stream>>>(hb, ssrc, sdst, rowstart, csr_src,
                                                     bias[l], Oh[l], Ol[l], N);
        Ah = Oh[l];
        Al = Ol[l];
    }

    // ---- pool + classifier ----
    hipMemsetAsync(pooled, 0, (size_t)NGRAPHS * FDIM * 4, stream);
    k_pool<<<(N + 127) / 128, 256, 0, stream>>>(P0h, P0l, batch, pooled, N);
    k_final<<<4, 256, 0, stream>>>(pooled, Wc, bc, (float*)d_out);
}

// Round 6
// 341.349 us; speedup vs baseline: 3.2656x; 1.1535x over previous
//
#include <hip/hip_runtime.h>
#include <hip/hip_bf16.h>

#define NNODES 50000
#define NEDGES 500000
#define INCH 128
#define HID 64
#define HEADS 4
#define FDIM 256
#define NGRAPHS 64
#define OUTCH 16
#define NEG_SLOPE 0.2f

#define BM 64
#define BN 256
#define BK 32

typedef float f32x4 __attribute__((ext_vector_type(4)));
typedef _Float16 f16x8 __attribute__((ext_vector_type(8)));
typedef _Float16 f16x4 __attribute__((ext_vector_type(4)));

__device__ inline void gld_lds16(const void* g, void* l) {
    __builtin_amdgcn_global_load_lds((__attribute__((address_space(1))) void*)g,
                                     (__attribute__((address_space(3))) void*)l, 16, 0, 0);
}

// ---------------- CSR build ----------------

__global__ void k_hist(const int* __restrict__ dst, int E, int* __restrict__ counts) {
    int i = blockIdx.x * blockDim.x + threadIdx.x;
    if (i < E) atomicAdd(&counts[dst[i]], 1);
}

__global__ __launch_bounds__(256) void k_blocksum(const int* __restrict__ counts, int N,
                                                  int* __restrict__ bsum) {
    int idx = blockIdx.x * 256 + threadIdx.x;
    int v = (idx < N) ? counts[idx] : 0;
#pragma unroll
    for (int off = 32; off; off >>= 1) v += __shfl_xor(v, off);
    __shared__ int wsum[4];
    if ((threadIdx.x & 63) == 0) wsum[threadIdx.x >> 6] = v;
    __syncthreads();
    if (threadIdx.x == 0) bsum[blockIdx.x] = wsum[0] + wsum[1] + wsum[2] + wsum[3];
}

// writes rowstart AND initializes cursor[n] = rowstart[n] (so scatter needs no memset)
__global__ __launch_bounds__(256) void k_scanfinal(const int* __restrict__ counts,
                                                   const int* __restrict__ bsum, int N,
                                                   int* __restrict__ rowstart,
                                                   int* __restrict__ cursor) {
    __shared__ int tmp[256];
    __shared__ int wsum[4];
    int t = threadIdx.x, b = blockIdx.x;
    int p = 0;
    for (int i = t; i < b; i += 256) p += bsum[i];
#pragma unroll
    for (int off = 32; off; off >>= 1) p += __shfl_xor(p, off);
    int idx = b * 256 + t;
    int v = (idx < N) ? counts[idx] : 0;
    tmp[t] = v;
    if ((t & 63) == 0) wsum[t >> 6] = p;
    __syncthreads();
    int bp = wsum[0] + wsum[1] + wsum[2] + wsum[3];
    for (int off = 1; off < 256; off <<= 1) {
        int u = (t >= off) ? tmp[t - off] : 0;
        __syncthreads();
        tmp[t] += u;
        __syncthreads();
    }
    if (idx < N) {
        int incl = bp + tmp[t];
        rowstart[idx + 1] = incl;
        cursor[idx] = incl - v;
    }
    if (idx == 0) rowstart[0] = 0;
}

__global__ void k_scatter(const int* __restrict__ src, const int* __restrict__ dst, int E,
                          int* __restrict__ cursor, int* __restrict__ csr_src) {
    int i = blockIdx.x * blockDim.x + threadIdx.x;
    if (i < E) {
        int p = atomicAdd(&cursor[dst[i]], 1);
        csr_src[p] = src[i];
    }
}

// ---------------- weight transpose to f16: W[K][256] -> Wt[256][K] ----------------

__global__ void k_wdecomp(const float* __restrict__ W, _Float16* __restrict__ Wt, int K) {
    int i = blockIdx.x * 256 + threadIdx.x;
    if (i >= K * 256) return;
    int k = i >> 8, n = i & 255;
    Wt[n * K + k] = (_Float16)W[i];
}

// ---------------- x -> f16 plane (row-major) ----------------

__global__ void k_adecomp(const float* __restrict__ X, _Float16* __restrict__ Xf, int total4) {
    int i = blockIdx.x * 256 + threadIdx.x;
    if (i >= total4) return;
    float4 v = ((const float4*)X)[i];
    f16x4 o = {(_Float16)v.x, (_Float16)v.y, (_Float16)v.z, (_Float16)v.w};
    ((f16x4*)Xf)[i] = o;
}

// ---------------- f16 MFMA GEMM, double-buffered gld_lds staging, fused scores ----------------
// H[M][256] = A[M][K] @ W[K][256]; A row-major f16, B transposed [256][K] f16.
// LDS linear [rows][BK] with 16B-chunk swizzle sc = lc ^ ((row>>1)&3) applied on the
// global source address (gld_lds writes linearly) and on the ds_read chunk index.
// Pipeline: stage(t+1) issued BEFORE compute(t); single barrier per step drains after MFMA.

__global__ __launch_bounds__(256) void k_gemm_mfma(
    const _Float16* __restrict__ A, const _Float16* __restrict__ B,
    const float* __restrict__ av, const float* __restrict__ dv,
    _Float16* __restrict__ Hf,
    float* __restrict__ ssrcO, float* __restrict__ sdstO, int M, int K) {
    __shared__ _Float16 sA[2][BM * BK];
    __shared__ _Float16 sB[2][BN * BK];

    const int t = threadIdx.x;
    const int row0 = blockIdx.x * BM;
    const int wv = t >> 6, ln = t & 63, lr = ln & 15, lk = ln >> 4;

    const int ar = wv * 16 + (ln >> 2);             // A tile row this lane stages
    const int alc = (ln & 3) ^ ((ar >> 1) & 3);     // logical 16B chunk to fetch
    const size_t agoff = (size_t)min(row0 + ar, M - 1) * K + alc * 8;
    const int brr = wv * 16 + (ln >> 2);
    const int fsc = lk ^ ((lr >> 1) & 3);           // fragment-read stored chunk

    f32x4 acc[4][4] = {};
    const int nt = K / BK;

#define STAGE(tt, p)                                                        \
    do {                                                                    \
        int _k0 = (tt)*BK;                                                  \
        gld_lds16(A + agoff + _k0, &sA[p][wv * 512]);                       \
        _Pragma("unroll") for (int _j = 0; _j < 4; ++_j) {                  \
            int _br = _j * 64 + brr;                                        \
            int _blc = (ln & 3) ^ ((_br >> 1) & 3);                         \
            gld_lds16(B + (size_t)_br * K + _k0 + _blc * 8,                 \
                      &sB[p][_j * 2048 + wv * 512]);                        \
        }                                                                   \
    } while (0)

    STAGE(0, 0);
    __syncthreads();
    for (int tt = 0; tt < nt; ++tt) {
        int cur = tt & 1;
        if (tt + 1 < nt) STAGE(tt + 1, cur ^ 1);  // flies during compute below

        f16x8 af[4];
#pragma unroll
        for (int mi = 0; mi < 4; ++mi)
            af[mi] = *(const f16x8*)&sA[cur][(mi * 16 + lr) * BK + fsc * 8];
#pragma unroll
        for (int ni = 0; ni < 4; ++ni) {
            f16x8 bf = *(const f16x8*)&sB[cur][(wv * 64 + ni * 16 + lr) * BK + fsc * 8];
#pragma unroll
            for (int mi = 0; mi < 4; ++mi)
                acc[mi][ni] = __builtin_amdgcn_mfma_f32_16x16x32_f16(af[mi], bf, acc[mi][ni], 0, 0, 0);
        }
        __syncthreads();  // drains vmcnt (t+1 loads) + lgkm after compute
    }
#undef STAGE

    // ---- epilogue: f16 H store + fused score partials ----
    float ps[4][4] = {}, pd[4][4] = {};
#pragma unroll
    for (int ni = 0; ni < 4; ++ni) {
        int col = wv * 64 + ni * 16 + lr;
        float a_s = av[col], a_d = dv[col];
#pragma unroll
        for (int mi = 0; mi < 4; ++mi) {
            f32x4 v = acc[mi][ni];
            int r = row0 + mi * 16 + lk * 4;
#pragma unroll
            for (int j = 0; j < 4; ++j) {
                if (r + j < M) Hf[(size_t)(r + j) * FDIM + col] = (_Float16)v[j];
                ps[mi][j] += v[j] * a_s;
                pd[mi][j] += v[j] * a_d;
            }
        }
    }
#pragma unroll
    for (int mi = 0; mi < 4; ++mi) {
#pragma unroll
        for (int j = 0; j < 4; ++j) {
            float s = ps[mi][j], q = pd[mi][j];
            s += __shfl_xor(s, 1); s += __shfl_xor(s, 2);
            s += __shfl_xor(s, 4); s += __shfl_xor(s, 8);
            q += __shfl_xor(q, 1); q += __shfl_xor(q, 2);
            q += __shfl_xor(q, 4); q += __shfl_xor(q, 8);
            if (lr == 0) {
                int r = row0 + mi * 16 + lk * 4 + j;
                if (r < M) {
                    ssrcO[r * HEADS + wv] = s;
                    sdstO[r * HEADS + wv] = q;
                }
            }
        }
    }
}

// ---------------- flash softmax + aggregation: predicated groups of 8 ----------------

__global__ __launch_bounds__(256) void k_aggregate(
    const _Float16* __restrict__ hf,
    const float* __restrict__ ssrc, const float* __restrict__ sdst,
    const int* __restrict__ rowstart, const int* __restrict__ csr_src,
    const float* __restrict__ bias,
    _Float16* __restrict__ outf, int N) {
    int wv = threadIdx.x >> 6, ln = threadIdx.x & 63;
    int n = blockIdx.x * 4 + wv;
    if (n >= N) return;
    int head = ln >> 4;
    int fo = head * 64 + (ln & 15) * 4;
    float sd = sdst[n * HEADS + head];
    float e = ssrc[n * HEADS + head] + sd;
    e = (e > 0.f) ? e : NEG_SLOPE * e;
    float m = e, d = 1.0f;
    f16x4 sv = *(const f16x4*)&hf[(size_t)n * FDIM + fo];
    float4 acc = make_float4((float)sv[0], (float)sv[1], (float)sv[2], (float)sv[3]);
    int r0 = rowstart[n], r1 = rowstart[n + 1];
    int cnt = r1 - r0;
    for (int base = 0; base < cnt; base += 8) {
        int s[8];
        f16x4 u[8];
        float c[8], w[8];
#pragma unroll
        for (int i = 0; i < 8; ++i) s[i] = csr_src[min(r0 + base + i, r1 - 1)];
#pragma unroll
        for (int i = 0; i < 8; ++i) u[i] = *(const f16x4*)&hf[(size_t)s[i] * FDIM + fo];
#pragma unroll
        for (int i = 0; i < 8; ++i) {
            float sc = ssrc[s[i] * HEADS + head] + sd;
            sc = (sc > 0.f) ? sc : NEG_SLOPE * sc;
            c[i] = (base + i < cnt) ? sc : -1e30f;
        }
        float mx = fmaxf(fmaxf(fmaxf(c[0], c[1]), fmaxf(c[2], c[3])),
                         fmaxf(fmaxf(c[4], c[5]), fmaxf(c[6], c[7])));
        float mn = fmaxf(m, mx);
        float wa = __expf(m - mn);
#pragma unroll
        for (int i = 0; i < 8; ++i) w[i] = __expf(c[i] - mn);
        float sx = 0.f, sy = 0.f, sz = 0.f, sw = 0.f, sdn = 0.f;
#pragma unroll
        for (int i = 0; i < 8; ++i) {
            sx += w[i] * (float)u[i][0];
            sy += w[i] * (float)u[i][1];
            sz += w[i] * (float)u[i][2];
            sw += w[i] * (float)u[i][3];
            sdn += w[i];
        }
        acc.x = acc.x * wa + sx;
        acc.y = acc.y * wa + sy;
        acc.z = acc.z * wa + sz;
        acc.w = acc.w * wa + sw;
        d = d * wa + sdn;
        m = mn;
    }
    float inv = 1.0f / d;
    float4 bv = *(const float4*)&bias[fo];
    f16x4 o;
    o[0] = (_Float16)fmaxf(acc.x * inv + bv.x, 0.f);
    o[1] = (_Float16)fmaxf(acc.y * inv + bv.y, 0.f);
    o[2] = (_Float16)fmaxf(acc.z * inv + bv.z, 0.f);
    o[3] = (_Float16)fmaxf(acc.w * inv + bv.w, 0.f);
    *(f16x4*)&outf[(size_t)n * FDIM + fo] = o;
}

// ---------------- pooling (batch sorted, f16 plane) ----------------

__global__ __launch_bounds__(256) void k_pool(const _Float16* __restrict__ hf,
                                              const int* __restrict__ batch,
                                              float* __restrict__ pooled, int N) {
    int f = threadIdx.x;
    int n0 = blockIdx.x * 128;
    if (n0 >= N) return;
    int n1 = min(n0 + 128, N);
    int g = batch[n0];
    float run = 0.f;
    for (int n = n0; n < n1; ++n) {
        int gn = batch[n];
        if (gn != g) {
            atomicAdd(&pooled[g * FDIM + f], run);
            run = 0.f;
            g = gn;
        }
        run += (float)hf[(size_t)n * FDIM + f];
    }
    atomicAdd(&pooled[g * FDIM + f], run);
}

// ---------------- final classifier ----------------

__global__ __launch_bounds__(256) void k_final(const float* __restrict__ pooled,
                                               const float* __restrict__ Wc,
                                               const float* __restrict__ bc,
                                               float* __restrict__ out) {
    int tid = blockIdx.x * 256 + threadIdx.x;
    int g = tid >> 4, o = tid & 15;
    float s = bc[o];
    for (int k = 0; k < FDIM; ++k) s += pooled[g * FDIM + k] * Wc[k * OUTCH + o];
    out[g * OUTCH + o] = s;
}

// ---------------- launch ----------------

extern "C" void kernel_launch(void* const* d_in, const int* in_sizes, int n_in,
                              void* d_out, int out_size, void* d_ws, size_t ws_size,
                              hipStream_t stream) {
    const float* x = (const float*)d_in[0];
    const int* edge_index = (const int*)d_in[2];
    const int* batch = (const int*)d_in[3];
    const float* W[3]    = {(const float*)d_in[4], (const float*)d_in[8],  (const float*)d_in[12]};
    const float* asrc[3] = {(const float*)d_in[5], (const float*)d_in[9],  (const float*)d_in[13]};
    const float* adst[3] = {(const float*)d_in[6], (const float*)d_in[10], (const float*)d_in[14]};
    const float* bias[3] = {(const float*)d_in[7], (const float*)d_in[11], (const float*)d_in[15]};
    const float* Wc = (const float*)d_in[16];
    const float* bc = (const float*)d_in[17];

    const int N = in_sizes[3];
    const int E = in_sizes[2] / 2;
    const int* e_src = edge_index;
    const int* e_dst = edge_index + E;

    char* ws = (char*)d_ws;
    size_t off = 0;
    _Float16* hb = (_Float16*)(ws + off); off += (size_t)N * FDIM * 2;   // 25.6 MB
    _Float16* xf = (_Float16*)(ws + off); off += (size_t)N * INCH * 2;   // 12.8 MB
    _Float16* P  = (_Float16*)(ws + off); off += (size_t)N * FDIM * 2;   // 25.6 MB
    float* ssrc = (float*)(ws + off); off += (size_t)N * HEADS * 4;
    float* sdst = (float*)(ws + off); off += (size_t)N * HEADS * 4;
    int* rowstart = (int*)(ws + off); off += ((size_t)(N + 1) * 4 + 255) / 256 * 256;
    int* counts = (int*)(ws + off); off += (size_t)N * 4;
    int* cursor = (int*)(ws + off); off += (size_t)N * 4;
    int* csr_src = (int*)(ws + off); off += (size_t)E * 4;
    float* pooled = (float*)(ws + off); off += (size_t)NGRAPHS * FDIM * 4;
    int* bsum = (int*)(ws + off); off += ((size_t)((N + 255) / 256) * 4 + 255) / 256 * 256;
    _Float16* Wt[3];
    int Ks[3] = {INCH, FDIM, FDIM};
    for (int l = 0; l < 3; ++l) {
        Wt[l] = (_Float16*)(ws + off); off += (size_t)256 * Ks[l] * 2;
    }

    const int nb = (N + 255) / 256;

    // ---- CSR build ----
    hipMemsetAsync(counts, 0, (size_t)N * 4, stream);
    k_hist<<<(E + 255) / 256, 256, 0, stream>>>(e_dst, E, counts);
    k_blocksum<<<nb, 256, 0, stream>>>(counts, N, bsum);
    k_scanfinal<<<nb, 256, 0, stream>>>(counts, bsum, N, rowstart, cursor);
    k_scatter<<<(E + 255) / 256, 256, 0, stream>>>(e_src, e_dst, E, cursor, csr_src);

    // ---- input + weight conversion to f16 planes ----
    k_adecomp<<<((N * INCH / 4) + 255) / 256, 256, 0, stream>>>(x, xf, N * INCH / 4);
    for (int l = 0; l < 3; ++l)
        k_wdecomp<<<(Ks[l] * 256 + 255) / 256, 256, 0, stream>>>(W[l], Wt[l], Ks[l]);

    // ---- 3 GAT layers ----
    const _Float16* Af = xf;
    for (int l = 0; l < 3; ++l) {
        int K = Ks[l];
        k_gemm_mfma<<<(N + BM - 1) / BM, 256, 0, stream>>>(Af, Wt[l], asrc[l], adst[l],
                                                           hb, ssrc, sdst, N, K);
        k_aggregate<<<(N + 3) / 4, 256, 0, stream>>>(hb, ssrc, sdst, rowstart, csr_src,
                                                     bias[l], P, N);
        Af = P;
    }

    // ---- pool + classifier ----
    hipMemsetAsync(pooled, 0, (size_t)NGRAPHS * FDIM * 4, stream);
    k_pool<<<(N + 127) / 128, 256, 0, stream>>>(P, batch, pooled, N);
    k_final<<<4, 256, 0, stream>>>(pooled, Wc, bc, (float*)d_out);
}